// Round 1
// baseline (1304.468 us; speedup 1.0000x reference)
//
#include <hip/hip_runtime.h>
#include <math.h>

#define NNODES 10000
#define HID    1024
#define NHEADS 4
#define NGRAPH 16
#define NCLS   10

// ---------------- CSR build ----------------

__global__ void k_hist(const int* __restrict__ dstArr, int* __restrict__ counts, int E) {
    int e = blockIdx.x * 256 + threadIdx.x;
    int total = E + NNODES;
    if (e < total) {
        int d = (e < E) ? dstArr[e] : (e - E);   // self-loops appended
        atomicAdd(&counts[d], 1);
    }
}

__global__ __launch_bounds__(1024) void k_scan(const int* __restrict__ counts,
                                               int* __restrict__ row_ptr, int N) {
    __shared__ int lds[1024];
    int t = threadIdx.x;
    const int C = (N + 1023) / 1024;
    int base = t * C;
    int s = 0;
    for (int i = 0; i < C; ++i)
        if (base + i < N) s += counts[base + i];
    lds[t] = s;
    __syncthreads();
    for (int off = 1; off < 1024; off <<= 1) {
        int add = (t >= off) ? lds[t - off] : 0;
        __syncthreads();
        lds[t] += add;
        __syncthreads();
    }
    int run = lds[t] - s;   // exclusive prefix
    for (int i = 0; i < C; ++i) {
        if (base + i < N) {
            row_ptr[base + i] = run;
            run += counts[base + i];
        }
    }
    if (t == 1023) row_ptr[N] = lds[1023];
}

__global__ void k_scatter(const int* __restrict__ srcArr, const int* __restrict__ dstArr,
                          const int* __restrict__ row_ptr, int* __restrict__ fill,
                          int* __restrict__ col, int E) {
    int e = blockIdx.x * 256 + threadIdx.x;
    int total = E + NNODES;
    if (e < total) {
        int s, d;
        if (e < E) { s = srcArr[e]; d = dstArr[e]; }
        else       { s = d = e - E; }
        int pos = row_ptr[d] + atomicAdd(&fill[d], 1);
        col[pos] = s;
    }
}

// ---------------- GEMM: C[M,1024] = A[M,K] * B[K,1024], f32 ----------------

__global__ __launch_bounds__(256) void k_gemm(const float* __restrict__ A,
                                              const float* __restrict__ B,
                                              float* __restrict__ C, int M, int K) {
    __shared__ float As[16][64];   // [k][m]
    __shared__ float Bs[16][64];   // [k][n]
    const int bm = blockIdx.y * 64;
    const int bn = blockIdx.x * 64;
    const int t  = threadIdx.x;
    const int tx = t % 16, ty = t / 16;

    // A-load mapping: 64 rows x 16 k, float4 per thread
    const int arow = t >> 2;
    const int akq  = (t & 3) * 4;
    // B-load mapping: 16 k-rows x 64 cols, float4 per thread
    const int bkr  = t >> 4;
    const int bnq  = (t & 15) * 4;

    float acc[4][4] = {};

    for (int k0 = 0; k0 < K; k0 += 16) {
        float4 av = make_float4(0.f, 0.f, 0.f, 0.f);
        if (bm + arow < M)
            av = *(const float4*)&A[(size_t)(bm + arow) * K + k0 + akq];
        float4 bv = *(const float4*)&B[(size_t)(k0 + bkr) * HID + bn + bnq];
        __syncthreads();
        As[akq + 0][arow] = av.x;
        As[akq + 1][arow] = av.y;
        As[akq + 2][arow] = av.z;
        As[akq + 3][arow] = av.w;
        *(float4*)&Bs[bkr][bnq] = bv;
        __syncthreads();
#pragma unroll
        for (int kk = 0; kk < 16; ++kk) {
            float4 a = *(const float4*)&As[kk][ty * 4];
            float4 b = *(const float4*)&Bs[kk][tx * 4];
            acc[0][0] += a.x * b.x; acc[0][1] += a.x * b.y; acc[0][2] += a.x * b.z; acc[0][3] += a.x * b.w;
            acc[1][0] += a.y * b.x; acc[1][1] += a.y * b.y; acc[1][2] += a.y * b.z; acc[1][3] += a.y * b.w;
            acc[2][0] += a.z * b.x; acc[2][1] += a.z * b.y; acc[2][2] += a.z * b.z; acc[2][3] += a.z * b.w;
            acc[3][0] += a.w * b.x; acc[3][1] += a.w * b.y; acc[3][2] += a.w * b.z; acc[3][3] += a.w * b.w;
        }
    }
#pragma unroll
    for (int i = 0; i < 4; ++i) {
        int row = bm + ty * 4 + i;
        if (row < M) {
            float4 o = make_float4(acc[i][0], acc[i][1], acc[i][2], acc[i][3]);
            *(float4*)&C[(size_t)row * HID + bn + tx * 4] = o;
        }
    }
}

// ---------------- per-node attention scalars ----------------

__global__ __launch_bounds__(256) void k_edotv(const float* __restrict__ proj,
                                               const float* __restrict__ asrc,
                                               const float* __restrict__ adst,
                                               float* __restrict__ esrc,
                                               float* __restrict__ edst) {
    int n = blockIdx.x;
    int t = threadIdx.x;
    float4 p  = *(const float4*)&proj[(size_t)n * HID + t * 4];
    float4 as = *(const float4*)&asrc[t * 4];
    float4 ad = *(const float4*)&adst[t * 4];
    float ds_ = p.x * as.x + p.y * as.y + p.z * as.z + p.w * as.w;
    float dd  = p.x * ad.x + p.y * ad.y + p.z * ad.z + p.w * ad.w;
#pragma unroll
    for (int off = 32; off > 0; off >>= 1) {
        ds_ += __shfl_down(ds_, off);
        dd  += __shfl_down(dd, off);
    }
    if ((t & 63) == 0) {
        esrc[n * NHEADS + (t >> 6)] = ds_;
        edst[n * NHEADS + (t >> 6)] = dd;
    }
}

// ---------------- aggregation (softmax over incoming edges + weighted sum) ----------------

__global__ __launch_bounds__(256) void k_agg(const float* __restrict__ proj,
                                             const float* __restrict__ esrc,
                                             const float* __restrict__ edst,
                                             const int* __restrict__ row_ptr,
                                             const int* __restrict__ col,
                                             const float* __restrict__ bias,
                                             float* __restrict__ hout) {
    int n = blockIdx.x;
    int t = threadIdx.x;
    int beg = row_ptr[n], end = row_ptr[n + 1];

    __shared__ float s_m[NHEADS], s_inv[NHEADS];

    if (t < 64) {
        float ed0 = edst[n * 4 + 0], ed1 = edst[n * 4 + 1];
        float ed2 = edst[n * 4 + 2], ed3 = edst[n * 4 + 3];
        float m0 = -1e30f, m1 = -1e30f, m2 = -1e30f, m3 = -1e30f;
        for (int j = beg + t; j < end; j += 64) {
            int s = col[j];
            float e0 = esrc[s * 4 + 0] + ed0; e0 = e0 > 0.f ? e0 : 0.2f * e0;
            float e1 = esrc[s * 4 + 1] + ed1; e1 = e1 > 0.f ? e1 : 0.2f * e1;
            float e2 = esrc[s * 4 + 2] + ed2; e2 = e2 > 0.f ? e2 : 0.2f * e2;
            float e3 = esrc[s * 4 + 3] + ed3; e3 = e3 > 0.f ? e3 : 0.2f * e3;
            m0 = fmaxf(m0, e0); m1 = fmaxf(m1, e1);
            m2 = fmaxf(m2, e2); m3 = fmaxf(m3, e3);
        }
#pragma unroll
        for (int off = 32; off > 0; off >>= 1) {
            m0 = fmaxf(m0, __shfl_xor(m0, off));
            m1 = fmaxf(m1, __shfl_xor(m1, off));
            m2 = fmaxf(m2, __shfl_xor(m2, off));
            m3 = fmaxf(m3, __shfl_xor(m3, off));
        }
        float d0 = 0.f, d1 = 0.f, d2 = 0.f, d3 = 0.f;
        for (int j = beg + t; j < end; j += 64) {
            int s = col[j];
            float e0 = esrc[s * 4 + 0] + ed0; e0 = e0 > 0.f ? e0 : 0.2f * e0;
            float e1 = esrc[s * 4 + 1] + ed1; e1 = e1 > 0.f ? e1 : 0.2f * e1;
            float e2 = esrc[s * 4 + 2] + ed2; e2 = e2 > 0.f ? e2 : 0.2f * e2;
            float e3 = esrc[s * 4 + 3] + ed3; e3 = e3 > 0.f ? e3 : 0.2f * e3;
            d0 += __expf(e0 - m0); d1 += __expf(e1 - m1);
            d2 += __expf(e2 - m2); d3 += __expf(e3 - m3);
        }
#pragma unroll
        for (int off = 32; off > 0; off >>= 1) {
            d0 += __shfl_xor(d0, off); d1 += __shfl_xor(d1, off);
            d2 += __shfl_xor(d2, off); d3 += __shfl_xor(d3, off);
        }
        if (t == 0) {
            s_m[0] = m0; s_m[1] = m1; s_m[2] = m2; s_m[3] = m3;
            s_inv[0] = 1.f / d0; s_inv[1] = 1.f / d1;
            s_inv[2] = 1.f / d2; s_inv[3] = 1.f / d3;
        }
    }
    __syncthreads();

    int h = t >> 6;
    float m = s_m[h], inv = s_inv[h];
    float edn = edst[n * 4 + h];
    float ax = 0.f, ay = 0.f, az = 0.f, aw = 0.f;
    for (int j = beg; j < end; ++j) {
        int s = col[j];
        float e = esrc[s * 4 + h] + edn;
        e = e > 0.f ? e : 0.2f * e;
        float alpha = __expf(e - m) * inv;
        float4 v = *(const float4*)&proj[(size_t)s * HID + t * 4];
        ax += alpha * v.x; ay += alpha * v.y;
        az += alpha * v.z; aw += alpha * v.w;
    }
    float4 b = *(const float4*)&bias[t * 4];
    float4 o;
    o.x = fmaxf(ax + b.x, 0.f);
    o.y = fmaxf(ay + b.y, 0.f);
    o.z = fmaxf(az + b.z, 0.f);
    o.w = fmaxf(aw + b.w, 0.f);
    *(float4*)&hout[(size_t)n * HID + t * 4] = o;
}

// ---------------- pooling + FC + log_softmax ----------------

__global__ void k_bounds(const int* __restrict__ batch, int* __restrict__ gstart,
                         int* __restrict__ gend, int N) {
    int n = blockIdx.x * 256 + threadIdx.x;
    if (n < N) {
        int g = batch[n];
        if (n == 0 || batch[n - 1] != g) gstart[g] = n;
        if (n == N - 1 || batch[n + 1] != g) gend[g] = n + 1;
    }
}

__global__ __launch_bounds__(256) void k_pool(const float* __restrict__ h,
                                              const int* __restrict__ gstart,
                                              const int* __restrict__ gend,
                                              float* __restrict__ pooled) {
    int g = blockIdx.x;
    int c = blockIdx.y * 256 + threadIdx.x;
    int s = gstart[g], e = gend[g];
    float sum = 0.f;
    for (int n = s; n < e; ++n) sum += h[(size_t)n * HID + c];
    float cnt = (float)(e - s);
    pooled[g * HID + c] = sum / fmaxf(cnt, 1.f);
}

__global__ __launch_bounds__(256) void k_fc(const float* __restrict__ pooled,
                                            const float* __restrict__ fcw,
                                            const float* __restrict__ fcb,
                                            float* __restrict__ out) {
    int g = blockIdx.x;
    int t = threadIdx.x;
    __shared__ float red[NCLS][256];
    float part[NCLS];
#pragma unroll
    for (int c = 0; c < NCLS; ++c) part[c] = 0.f;
    for (int k = t; k < HID; k += 256) {
        float v = pooled[g * HID + k];
#pragma unroll
        for (int c = 0; c < NCLS; ++c) part[c] += v * fcw[k * NCLS + c];
    }
#pragma unroll
    for (int c = 0; c < NCLS; ++c) red[c][t] = part[c];
    __syncthreads();
    for (int off = 128; off > 0; off >>= 1) {
        if (t < off) {
#pragma unroll
            for (int c = 0; c < NCLS; ++c) red[c][t] += red[c][t + off];
        }
        __syncthreads();
    }
    if (t == 0) {
        float logits[NCLS];
        float mx = -1e30f;
#pragma unroll
        for (int c = 0; c < NCLS; ++c) {
            logits[c] = red[c][0] + fcb[c];
            mx = fmaxf(mx, logits[c]);
        }
        float se = 0.f;
#pragma unroll
        for (int c = 0; c < NCLS; ++c) se += expf(logits[c] - mx);
        float lse = mx + logf(se);
#pragma unroll
        for (int c = 0; c < NCLS; ++c) out[g * NCLS + c] = logits[c] - lse;
    }
}

// ---------------- launch ----------------

extern "C" void kernel_launch(void* const* d_in, const int* in_sizes, int n_in,
                              void* d_out, int out_size, void* d_ws, size_t ws_size,
                              hipStream_t stream) {
    const float* x    = (const float*)d_in[0];
    const int*   ei   = (const int*)d_in[1];
    const int*   batch= (const int*)d_in[2];
    const float* W0   = (const float*)d_in[3];
    const float* W1   = (const float*)d_in[4];
    const float* W2   = (const float*)d_in[5];
    const float* asrc = (const float*)d_in[6];
    const float* adst = (const float*)d_in[7];
    const float* bias = (const float*)d_in[8];
    const float* fcw  = (const float*)d_in[9];
    const float* fcb  = (const float*)d_in[10];
    float* out = (float*)d_out;

    const int E = in_sizes[1] / 2;
    const int N = NNODES;
    const int NE = E + N;

    // workspace layout
    char* ws = (char*)d_ws;
    size_t off = 0;
    auto alloc = [&](size_t bytes) { void* p = ws + off; off += (bytes + 255) & ~(size_t)255; return p; };
    float* bufA   = (float*)alloc((size_t)N * HID * 4);   // proj
    float* bufB   = (float*)alloc((size_t)N * HID * 4);   // h ping-pong
    float* esrc   = (float*)alloc((size_t)N * NHEADS * 4);
    float* edst   = (float*)alloc((size_t)N * NHEADS * 4);
    int*   counts = (int*)alloc((size_t)N * 4);
    int*   row_ptr= (int*)alloc((size_t)(N + 1) * 4);
    int*   fill   = (int*)alloc((size_t)N * 4);
    int*   col    = (int*)alloc((size_t)NE * 4);
    int*   gstart = (int*)alloc(NGRAPH * 4);
    int*   gend   = (int*)alloc(NGRAPH * 4);
    float* pooled = (float*)alloc(NGRAPH * HID * 4);
    (void)ws_size;

    const int* srcArr = ei;
    const int* dstArr = ei + E;

    // CSR build
    hipMemsetAsync(counts, 0, (size_t)N * 4, stream);
    hipMemsetAsync(fill,   0, (size_t)N * 4, stream);
    hipMemsetAsync(gstart, 0, NGRAPH * 4, stream);
    hipMemsetAsync(gend,   0, NGRAPH * 4, stream);
    int nbE = (NE + 255) / 256;
    k_hist<<<nbE, 256, 0, stream>>>(dstArr, counts, E);
    k_scan<<<1, 1024, 0, stream>>>(counts, row_ptr, N);
    k_scatter<<<nbE, 256, 0, stream>>>(srcArr, dstArr, row_ptr, fill, col, E);

    dim3 gemmGrid(HID / 64, (N + 63) / 64);

    // layer 0: x[N,512] @ W0 -> bufA ; agg -> bufB
    k_gemm<<<gemmGrid, 256, 0, stream>>>(x, W0, bufA, N, 512);
    k_edotv<<<N, 256, 0, stream>>>(bufA, asrc + 0 * HID, adst + 0 * HID, esrc, edst);
    k_agg<<<N, 256, 0, stream>>>(bufA, esrc, edst, row_ptr, col, bias + 0 * HID, bufB);

    // layer 1
    k_gemm<<<gemmGrid, 256, 0, stream>>>(bufB, W1, bufA, N, HID);
    k_edotv<<<N, 256, 0, stream>>>(bufA, asrc + 1 * HID, adst + 1 * HID, esrc, edst);
    k_agg<<<N, 256, 0, stream>>>(bufA, esrc, edst, row_ptr, col, bias + 1 * HID, bufB);

    // layer 2
    k_gemm<<<gemmGrid, 256, 0, stream>>>(bufB, W2, bufA, N, HID);
    k_edotv<<<N, 256, 0, stream>>>(bufA, asrc + 2 * HID, adst + 2 * HID, esrc, edst);
    k_agg<<<N, 256, 0, stream>>>(bufA, esrc, edst, row_ptr, col, bias + 2 * HID, bufB);

    // pool + FC + log_softmax
    k_bounds<<<(N + 255) / 256, 256, 0, stream>>>(batch, gstart, gend, N);
    dim3 poolGrid(NGRAPH, HID / 256);
    k_pool<<<poolGrid, 256, 0, stream>>>(bufB, gstart, gend, pooled);
    k_fc<<<NGRAPH, 256, 0, stream>>>(pooled, fcw, fcb, out);
}

// Round 2
// 653.717 us; speedup vs baseline: 1.9955x; 1.9955x over previous
//
#include <hip/hip_runtime.h>
#include <math.h>

#define NNODES 10000
#define HID    1024
#define NHEADS 4
#define NGRAPH 16
#define NCLS   10

typedef __attribute__((ext_vector_type(8))) short bf16x8;
typedef __attribute__((ext_vector_type(4))) float f32x4;

__device__ __forceinline__ ushort bf16r(float f) {
    union { float f; unsigned u; } x; x.f = f;
    unsigned r = x.u + 0x7FFFu + ((x.u >> 16) & 1u);
    return (ushort)(r >> 16);
}
__device__ __forceinline__ float bf16f(ushort u) {
    union { unsigned u; float f; } x; x.u = ((unsigned)u) << 16;
    return x.f;
}

// ---------------- CSR build ----------------

__global__ void k_hist(const int* __restrict__ dstArr, int* __restrict__ counts, int E) {
    int e = blockIdx.x * 256 + threadIdx.x;
    int total = E + NNODES;
    if (e < total) {
        int d = (e < E) ? dstArr[e] : (e - E);   // self-loops appended
        atomicAdd(&counts[d], 1);
    }
}

__global__ __launch_bounds__(1024) void k_scan(const int* __restrict__ counts,
                                               int* __restrict__ row_ptr, int N) {
    __shared__ int lds[1024];
    int t = threadIdx.x;
    const int C = (N + 1023) / 1024;
    int base = t * C;
    int s = 0;
    for (int i = 0; i < C; ++i)
        if (base + i < N) s += counts[base + i];
    lds[t] = s;
    __syncthreads();
    for (int off = 1; off < 1024; off <<= 1) {
        int add = (t >= off) ? lds[t - off] : 0;
        __syncthreads();
        lds[t] += add;
        __syncthreads();
    }
    int run = lds[t] - s;   // exclusive prefix
    for (int i = 0; i < C; ++i) {
        if (base + i < N) {
            row_ptr[base + i] = run;
            run += counts[base + i];
        }
    }
    if (t == 1023) row_ptr[N] = lds[1023];
}

__global__ void k_scatter(const int* __restrict__ srcArr, const int* __restrict__ dstArr,
                          const int* __restrict__ row_ptr, int* __restrict__ fill,
                          int* __restrict__ col, int E) {
    int e = blockIdx.x * 256 + threadIdx.x;
    int total = E + NNODES;
    if (e < total) {
        int s, d;
        if (e < E) { s = srcArr[e]; d = dstArr[e]; }
        else       { s = d = e - E; }
        int pos = row_ptr[d] + atomicAdd(&fill[d], 1);
        col[pos] = s;
    }
}

// ---------------- conversions ----------------

__global__ void k_f32_to_bf16(const float* __restrict__ in, ushort* __restrict__ out, int n4) {
    int i = blockIdx.x * 256 + threadIdx.x;
    if (i < n4) {
        float4 v = ((const float4*)in)[i];
        ushort4 o;
        o.x = bf16r(v.x); o.y = bf16r(v.y); o.z = bf16r(v.z); o.w = bf16r(v.w);
        ((ushort4*)out)[i] = o;
    }
}

// W [K][1024] f32 -> Wt [1024][K] bf16
__global__ __launch_bounds__(256) void k_wT(const float* __restrict__ W, ushort* __restrict__ Wt, int K) {
    __shared__ ushort tile[32][33];
    int bx = blockIdx.x;              // along N (1024/32)
    int by = blockIdx.y;              // along K
    int tx = threadIdx.x & 31, ty = threadIdx.x >> 5;   // 32 x 8
#pragma unroll
    for (int i = 0; i < 32; i += 8) {
        int k  = by * 32 + ty + i;
        int nn = bx * 32 + tx;
        tile[ty + i][tx] = bf16r(W[(size_t)k * HID + nn]);
    }
    __syncthreads();
#pragma unroll
    for (int i = 0; i < 32; i += 8) {
        int nn = bx * 32 + ty + i;
        int k  = by * 32 + tx;
        Wt[(size_t)nn * K + k] = tile[tx][ty + i];
    }
}

// ---------------- bf16 MFMA GEMM: C[M,1024] = A[M,K] * Bt[1024,K]^T ----------------
// 128x128 tile, BK=64, 4 waves, each wave 64x64 (4x4 of 16x16x32 MFMA).
// LDS XOR-swizzle (chunk ^= row&7) applied via pre-swizzled global source
// (global_load_lds writes linearly) + swizzled ds_read.

#define BM 128
#define BN 128
#define BK 64

__global__ __launch_bounds__(256) void k_gemm_bf16(const ushort* __restrict__ A,
                                                   const ushort* __restrict__ Bt,
                                                   float* __restrict__ C, int M, int K) {
    __shared__ ushort As[BM * BK];
    __shared__ ushort Bs[BN * BK];
    const int t    = threadIdx.x;
    const int lane = t & 63;
    const int w    = t >> 6;
    const int wr   = w >> 1, wc = w & 1;
    const int bm   = blockIdx.y * BM;
    const int bn   = blockIdx.x * BN;

    f32x4 acc[4][4] = {};

    const int r_  = t >> 3;          // row within stage issue block (fc = i*256+t -> r = fc>>3 = i*32 + t>>3)
    const int cp_ = t & 7;           // linear chunk within row

    for (int k0 = 0; k0 < K; k0 += BK) {
        __syncthreads();             // LDS free for overwrite
#pragma unroll
        for (int i = 0; i < 4; ++i) {
            int fc = i * 256 + t;
            int r  = i * 32 + r_;
            int c  = cp_ ^ (r & 7);  // inverse-swizzled source chunk
            int ga = bm + r; if (ga >= M) ga = M - 1;
            __builtin_amdgcn_global_load_lds(
                (const __attribute__((address_space(1))) unsigned*)&A[(size_t)ga * K + k0 + c * 8],
                (__attribute__((address_space(3))) unsigned*)&As[fc * 8], 16, 0, 0);
            __builtin_amdgcn_global_load_lds(
                (const __attribute__((address_space(1))) unsigned*)&Bt[(size_t)(bn + r) * K + k0 + c * 8],
                (__attribute__((address_space(3))) unsigned*)&Bs[fc * 8], 16, 0, 0);
        }
        __syncthreads();             // staging visible (compiler drains vmcnt)

#pragma unroll
        for (int s = 0; s < 2; ++s) {
            const int kc = s * 4 + (lane >> 4);     // k-chunk index 0..7
            bf16x8 a[4], b[4];
#pragma unroll
            for (int m = 0; m < 4; ++m) {
                int row = wr * 64 + m * 16 + (lane & 15);
                int ch  = kc ^ (row & 7);
                a[m] = *(const bf16x8*)&As[row * BK + ch * 8];
            }
#pragma unroll
            for (int n = 0; n < 4; ++n) {
                int cl = wc * 64 + n * 16 + (lane & 15);
                int ch = kc ^ (cl & 7);
                b[n] = *(const bf16x8*)&Bs[cl * BK + ch * 8];
            }
#pragma unroll
            for (int m = 0; m < 4; ++m)
#pragma unroll
                for (int n = 0; n < 4; ++n)
                    acc[m][n] = __builtin_amdgcn_mfma_f32_16x16x32_bf16(a[m], b[n], acc[m][n], 0, 0, 0);
        }
    }

    // C/D layout: col = lane&15, row = (lane>>4)*4 + j   [m89-verified]
#pragma unroll
    for (int m = 0; m < 4; ++m) {
        int row0 = bm + wr * 64 + m * 16 + (lane >> 4) * 4;
#pragma unroll
        for (int n = 0; n < 4; ++n) {
            int coln = bn + wc * 64 + n * 16 + (lane & 15);
#pragma unroll
            for (int j = 0; j < 4; ++j) {
                int row = row0 + j;
                if (row < M) C[(size_t)row * HID + coln] = acc[m][n][j];
            }
        }
    }
}

// ---------------- per-node attention scalars ----------------

__global__ __launch_bounds__(256) void k_edotv(const float* __restrict__ proj,
                                               const float* __restrict__ asrc,
                                               const float* __restrict__ adst,
                                               float* __restrict__ esrc,
                                               float* __restrict__ edst) {
    int n = blockIdx.x;
    int t = threadIdx.x;
    float4 p  = *(const float4*)&proj[(size_t)n * HID + t * 4];
    float4 as = *(const float4*)&asrc[t * 4];
    float4 ad = *(const float4*)&adst[t * 4];
    float ds_ = p.x * as.x + p.y * as.y + p.z * as.z + p.w * as.w;
    float dd  = p.x * ad.x + p.y * ad.y + p.z * ad.z + p.w * ad.w;
#pragma unroll
    for (int off = 32; off > 0; off >>= 1) {
        ds_ += __shfl_down(ds_, off);
        dd  += __shfl_down(dd, off);
    }
    if ((t & 63) == 0) {
        esrc[n * NHEADS + (t >> 6)] = ds_;
        edst[n * NHEADS + (t >> 6)] = dd;
    }
}

// ---------------- aggregation (softmax over incoming edges + weighted sum) ----------------

__global__ __launch_bounds__(256) void k_agg(const float* __restrict__ proj,
                                             const float* __restrict__ esrc,
                                             const float* __restrict__ edst,
                                             const int* __restrict__ row_ptr,
                                             const int* __restrict__ col,
                                             const float* __restrict__ bias,
                                             ushort* __restrict__ hb16) {
    int n = blockIdx.x;
    int t = threadIdx.x;
    int beg = row_ptr[n], end = row_ptr[n + 1];

    __shared__ float s_m[NHEADS], s_inv[NHEADS];

    if (t < 64) {
        float ed0 = edst[n * 4 + 0], ed1 = edst[n * 4 + 1];
        float ed2 = edst[n * 4 + 2], ed3 = edst[n * 4 + 3];
        float m0 = -1e30f, m1 = -1e30f, m2 = -1e30f, m3 = -1e30f;
        for (int j = beg + t; j < end; j += 64) {
            int s = col[j];
            float e0 = esrc[s * 4 + 0] + ed0; e0 = e0 > 0.f ? e0 : 0.2f * e0;
            float e1 = esrc[s * 4 + 1] + ed1; e1 = e1 > 0.f ? e1 : 0.2f * e1;
            float e2 = esrc[s * 4 + 2] + ed2; e2 = e2 > 0.f ? e2 : 0.2f * e2;
            float e3 = esrc[s * 4 + 3] + ed3; e3 = e3 > 0.f ? e3 : 0.2f * e3;
            m0 = fmaxf(m0, e0); m1 = fmaxf(m1, e1);
            m2 = fmaxf(m2, e2); m3 = fmaxf(m3, e3);
        }
#pragma unroll
        for (int off = 32; off > 0; off >>= 1) {
            m0 = fmaxf(m0, __shfl_xor(m0, off));
            m1 = fmaxf(m1, __shfl_xor(m1, off));
            m2 = fmaxf(m2, __shfl_xor(m2, off));
            m3 = fmaxf(m3, __shfl_xor(m3, off));
        }
        float d0 = 0.f, d1 = 0.f, d2 = 0.f, d3 = 0.f;
        for (int j = beg + t; j < end; j += 64) {
            int s = col[j];
            float e0 = esrc[s * 4 + 0] + ed0; e0 = e0 > 0.f ? e0 : 0.2f * e0;
            float e1 = esrc[s * 4 + 1] + ed1; e1 = e1 > 0.f ? e1 : 0.2f * e1;
            float e2 = esrc[s * 4 + 2] + ed2; e2 = e2 > 0.f ? e2 : 0.2f * e2;
            float e3 = esrc[s * 4 + 3] + ed3; e3 = e3 > 0.f ? e3 : 0.2f * e3;
            d0 += __expf(e0 - m0); d1 += __expf(e1 - m1);
            d2 += __expf(e2 - m2); d3 += __expf(e3 - m3);
        }
#pragma unroll
        for (int off = 32; off > 0; off >>= 1) {
            d0 += __shfl_xor(d0, off); d1 += __shfl_xor(d1, off);
            d2 += __shfl_xor(d2, off); d3 += __shfl_xor(d3, off);
        }
        if (t == 0) {
            s_m[0] = m0; s_m[1] = m1; s_m[2] = m2; s_m[3] = m3;
            s_inv[0] = 1.f / d0; s_inv[1] = 1.f / d1;
            s_inv[2] = 1.f / d2; s_inv[3] = 1.f / d3;
        }
    }
    __syncthreads();

    int h = t >> 6;
    float m = s_m[h], inv = s_inv[h];
    float edn = edst[n * 4 + h];
    float ax = 0.f, ay = 0.f, az = 0.f, aw = 0.f;
    for (int j = beg; j < end; ++j) {
        int s = col[j];
        float e = esrc[s * 4 + h] + edn;
        e = e > 0.f ? e : 0.2f * e;
        float alpha = __expf(e - m) * inv;
        float4 v = *(const float4*)&proj[(size_t)s * HID + t * 4];
        ax += alpha * v.x; ay += alpha * v.y;
        az += alpha * v.z; aw += alpha * v.w;
    }
    float4 b = *(const float4*)&bias[t * 4];
    ushort4 o;
    o.x = bf16r(fmaxf(ax + b.x, 0.f));
    o.y = bf16r(fmaxf(ay + b.y, 0.f));
    o.z = bf16r(fmaxf(az + b.z, 0.f));
    o.w = bf16r(fmaxf(aw + b.w, 0.f));
    *(ushort4*)&hb16[(size_t)n * HID + t * 4] = o;
}

// ---------------- pooling + FC + log_softmax ----------------

__global__ void k_bounds(const int* __restrict__ batch, int* __restrict__ gstart,
                         int* __restrict__ gend, int N) {
    int n = blockIdx.x * 256 + threadIdx.x;
    if (n < N) {
        int g = batch[n];
        if (n == 0 || batch[n - 1] != g) gstart[g] = n;
        if (n == N - 1 || batch[n + 1] != g) gend[g] = n + 1;
    }
}

__global__ __launch_bounds__(256) void k_pool(const ushort* __restrict__ h,
                                              const int* __restrict__ gstart,
                                              const int* __restrict__ gend,
                                              float* __restrict__ pooled) {
    int g = blockIdx.x;
    int c = blockIdx.y * 256 + threadIdx.x;
    int s = gstart[g], e = gend[g];
    float sum = 0.f;
    for (int n = s; n < e; ++n) sum += bf16f(h[(size_t)n * HID + c]);
    float cnt = (float)(e - s);
    pooled[g * HID + c] = sum / fmaxf(cnt, 1.f);
}

__global__ __launch_bounds__(256) void k_fc(const float* __restrict__ pooled,
                                            const float* __restrict__ fcw,
                                            const float* __restrict__ fcb,
                                            float* __restrict__ out) {
    int g = blockIdx.x;
    int t = threadIdx.x;
    __shared__ float red[NCLS][256];
    float part[NCLS];
#pragma unroll
    for (int c = 0; c < NCLS; ++c) part[c] = 0.f;
    for (int k = t; k < HID; k += 256) {
        float v = pooled[g * HID + k];
#pragma unroll
        for (int c = 0; c < NCLS; ++c) part[c] += v * fcw[k * NCLS + c];
    }
#pragma unroll
    for (int c = 0; c < NCLS; ++c) red[c][t] = part[c];
    __syncthreads();
    for (int off = 128; off > 0; off >>= 1) {
        if (t < off) {
#pragma unroll
            for (int c = 0; c < NCLS; ++c) red[c][t] += red[c][t + off];
        }
        __syncthreads();
    }
    if (t == 0) {
        float logits[NCLS];
        float mx = -1e30f;
#pragma unroll
        for (int c = 0; c < NCLS; ++c) {
            logits[c] = red[c][0] + fcb[c];
            mx = fmaxf(mx, logits[c]);
        }
        float se = 0.f;
#pragma unroll
        for (int c = 0; c < NCLS; ++c) se += expf(logits[c] - mx);
        float lse = mx + logf(se);
#pragma unroll
        for (int c = 0; c < NCLS; ++c) out[g * NCLS + c] = logits[c] - lse;
    }
}

// ---------------- launch ----------------

extern "C" void kernel_launch(void* const* d_in, const int* in_sizes, int n_in,
                              void* d_out, int out_size, void* d_ws, size_t ws_size,
                              hipStream_t stream) {
    const float* x    = (const float*)d_in[0];
    const int*   ei   = (const int*)d_in[1];
    const int*   batch= (const int*)d_in[2];
    const float* W0   = (const float*)d_in[3];
    const float* W1   = (const float*)d_in[4];
    const float* W2   = (const float*)d_in[5];
    const float* asrc = (const float*)d_in[6];
    const float* adst = (const float*)d_in[7];
    const float* bias = (const float*)d_in[8];
    const float* fcw  = (const float*)d_in[9];
    const float* fcb  = (const float*)d_in[10];
    float* out = (float*)d_out;

    const int E = in_sizes[1] / 2;
    const int N = NNODES;
    const int NE = E + N;

    // workspace layout
    char* ws = (char*)d_ws;
    size_t off = 0;
    auto alloc = [&](size_t bytes) { void* p = ws + off; off += (bytes + 255) & ~(size_t)255; return p; };
    float*  proj   = (float*)alloc((size_t)N * HID * 4);        // GEMM C output (f32)
    ushort* hb16   = (ushort*)alloc((size_t)N * HID * 2);       // layer output (bf16)
    ushort* xb16   = (ushort*)alloc((size_t)N * 512 * 2);
    ushort* w0t    = (ushort*)alloc((size_t)HID * 512 * 2);
    ushort* w1t    = (ushort*)alloc((size_t)HID * HID * 2);
    ushort* w2t    = (ushort*)alloc((size_t)HID * HID * 2);
    float*  esrc   = (float*)alloc((size_t)N * NHEADS * 4);
    float*  edst   = (float*)alloc((size_t)N * NHEADS * 4);
    int*    counts = (int*)alloc((size_t)N * 4);
    int*    row_ptr= (int*)alloc((size_t)(N + 1) * 4);
    int*    fill   = (int*)alloc((size_t)N * 4);
    int*    col    = (int*)alloc((size_t)NE * 4);
    int*    gstart = (int*)alloc(NGRAPH * 4);
    int*    gend   = (int*)alloc(NGRAPH * 4);
    float*  pooled = (float*)alloc(NGRAPH * HID * 4);
    (void)ws_size;

    const int* srcArr = ei;
    const int* dstArr = ei + E;

    // CSR build
    hipMemsetAsync(counts, 0, (size_t)N * 4, stream);
    hipMemsetAsync(fill,   0, (size_t)N * 4, stream);
    hipMemsetAsync(gstart, 0, NGRAPH * 4, stream);
    hipMemsetAsync(gend,   0, NGRAPH * 4, stream);
    int nbE = (NE + 255) / 256;
    k_hist<<<nbE, 256, 0, stream>>>(dstArr, counts, E);
    k_scan<<<1, 1024, 0, stream>>>(counts, row_ptr, N);
    k_scatter<<<nbE, 256, 0, stream>>>(srcArr, dstArr, row_ptr, fill, col, E);

    // conversions
    k_f32_to_bf16<<<(N * 512 / 4 + 255) / 256, 256, 0, stream>>>(x, xb16, N * 512 / 4);
    k_wT<<<dim3(32, 512 / 32), 256, 0, stream>>>(W0, w0t, 512);
    k_wT<<<dim3(32, HID / 32), 256, 0, stream>>>(W1, w1t, HID);
    k_wT<<<dim3(32, HID / 32), 256, 0, stream>>>(W2, w2t, HID);

    dim3 gemmGrid(HID / BN, (N + BM - 1) / BM);

    // layer 0
    k_gemm_bf16<<<gemmGrid, 256, 0, stream>>>(xb16, w0t, proj, N, 512);
    k_edotv<<<N, 256, 0, stream>>>(proj, asrc + 0 * HID, adst + 0 * HID, esrc, edst);
    k_agg<<<N, 256, 0, stream>>>(proj, esrc, edst, row_ptr, col, bias + 0 * HID, hb16);

    // layer 1
    k_gemm_bf16<<<gemmGrid, 256, 0, stream>>>(hb16, w1t, proj, N, HID);
    k_edotv<<<N, 256, 0, stream>>>(proj, asrc + 1 * HID, adst + 1 * HID, esrc, edst);
    k_agg<<<N, 256, 0, stream>>>(proj, esrc, edst, row_ptr, col, bias + 1 * HID, hb16);

    // layer 2
    k_gemm_bf16<<<gemmGrid, 256, 0, stream>>>(hb16, w2t, proj, N, HID);
    k_edotv<<<N, 256, 0, stream>>>(proj, asrc + 2 * HID, adst + 2 * HID, esrc, edst);
    k_agg<<<N, 256, 0, stream>>>(proj, esrc, edst, row_ptr, col, bias + 2 * HID, hb16);

    // pool + FC + log_softmax
    k_bounds<<<(N + 255) / 256, 256, 0, stream>>>(batch, gstart, gend, N);
    dim3 poolGrid(NGRAPH, HID / 256);
    k_pool<<<poolGrid, 256, 0, stream>>>(hb16, gstart, gend, pooled);
    k_fc<<<NGRAPH, 256, 0, stream>>>(pooled, fcw, fcb, out);
}

// Round 3
// 367.479 us; speedup vs baseline: 3.5498x; 1.7789x over previous
//
#include <hip/hip_runtime.h>
#include <math.h>

#define NNODES 10000
#define HID    1024
#define NHEADS 4
#define NGRAPH 16
#define NCLS   10

typedef __attribute__((ext_vector_type(8))) short bf16x8;
typedef __attribute__((ext_vector_type(4))) float f32x4;

__device__ __forceinline__ ushort bf16r(float f) {
    union { float f; unsigned u; } x; x.f = f;
    unsigned r = x.u + 0x7FFFu + ((x.u >> 16) & 1u);
    return (ushort)(r >> 16);
}
__device__ __forceinline__ float bf16f(ushort u) {
    union { unsigned u; float f; } x; x.u = ((unsigned)u) << 16;
    return x.f;
}

// ---------------- CSR build ----------------

__global__ void k_hist(const int* __restrict__ dstArr, int* __restrict__ counts, int E) {
    int e = blockIdx.x * 256 + threadIdx.x;
    int total = E + NNODES;
    if (e < total) {
        int d = (e < E) ? dstArr[e] : (e - E);   // self-loops appended
        atomicAdd(&counts[d], 1);
    }
}

__global__ __launch_bounds__(1024) void k_scan(const int* __restrict__ counts,
                                               int* __restrict__ row_ptr, int N) {
    __shared__ int lds[1024];
    int t = threadIdx.x;
    const int C = (N + 1023) / 1024;
    int base = t * C;
    int s = 0;
    for (int i = 0; i < C; ++i)
        if (base + i < N) s += counts[base + i];
    lds[t] = s;
    __syncthreads();
    for (int off = 1; off < 1024; off <<= 1) {
        int add = (t >= off) ? lds[t - off] : 0;
        __syncthreads();
        lds[t] += add;
        __syncthreads();
    }
    int run = lds[t] - s;   // exclusive prefix
    for (int i = 0; i < C; ++i) {
        if (base + i < N) {
            row_ptr[base + i] = run;
            run += counts[base + i];
        }
    }
    if (t == 1023) row_ptr[N] = lds[1023];
}

__global__ void k_scatter(const int* __restrict__ srcArr, const int* __restrict__ dstArr,
                          const int* __restrict__ row_ptr, int* __restrict__ fill,
                          int* __restrict__ col, int E) {
    int e = blockIdx.x * 256 + threadIdx.x;
    int total = E + NNODES;
    if (e < total) {
        int s, d;
        if (e < E) { s = srcArr[e]; d = dstArr[e]; }
        else       { s = d = e - E; }
        int pos = row_ptr[d] + atomicAdd(&fill[d], 1);
        col[pos] = s;
    }
}

// ---------------- conversions ----------------

__global__ void k_f32_to_bf16(const float* __restrict__ in, ushort* __restrict__ out, int n4) {
    int i = blockIdx.x * 256 + threadIdx.x;
    if (i < n4) {
        float4 v = ((const float4*)in)[i];
        ushort4 o;
        o.x = bf16r(v.x); o.y = bf16r(v.y); o.z = bf16r(v.z); o.w = bf16r(v.w);
        ((ushort4*)out)[i] = o;
    }
}

// W [K][1024] f32 -> Wt [1024][K] bf16
__global__ __launch_bounds__(256) void k_wT(const float* __restrict__ W, ushort* __restrict__ Wt, int K) {
    __shared__ ushort tile[32][33];
    int bx = blockIdx.x;              // along N (1024/32)
    int by = blockIdx.y;              // along K
    int tx = threadIdx.x & 31, ty = threadIdx.x >> 5;   // 32 x 8
#pragma unroll
    for (int i = 0; i < 32; i += 8) {
        int k  = by * 32 + ty + i;
        int nn = bx * 32 + tx;
        tile[ty + i][tx] = bf16r(W[(size_t)k * HID + nn]);
    }
    __syncthreads();
#pragma unroll
    for (int i = 0; i < 32; i += 8) {
        int nn = bx * 32 + ty + i;
        int k  = by * 32 + tx;
        Wt[(size_t)nn * K + k] = tile[tx][ty + i];
    }
}

// ---------------- bf16 MFMA GEMM: C[M,1024] = A[M,K] * Bt[1024,K]^T, bf16 out ----------------
// 128x128 tile, BK=64, 4 waves, each wave 64x64 (4x4 of 16x16x32 MFMA).
// LDS XOR-swizzle (chunk ^= row&7) applied via pre-swizzled global source
// (global_load_lds writes linearly) + swizzled ds_read.

#define BM 128
#define BN 128
#define BK 64

__global__ __launch_bounds__(256) void k_gemm_bf16(const ushort* __restrict__ A,
                                                   const ushort* __restrict__ Bt,
                                                   ushort* __restrict__ C, int M, int K) {
    __shared__ ushort As[BM * BK];
    __shared__ ushort Bs[BN * BK];
    const int t    = threadIdx.x;
    const int lane = t & 63;
    const int w    = t >> 6;
    const int wr   = w >> 1, wc = w & 1;
    const int bm   = blockIdx.y * BM;
    const int bn   = blockIdx.x * BN;

    f32x4 acc[4][4] = {};

    const int r_  = t >> 3;          // fc = i*256+t -> row = i*32 + t>>3
    const int cp_ = t & 7;           // linear chunk within row

    for (int k0 = 0; k0 < K; k0 += BK) {
        __syncthreads();             // LDS free for overwrite
#pragma unroll
        for (int i = 0; i < 4; ++i) {
            int fc = i * 256 + t;
            int r  = i * 32 + r_;
            int c  = cp_ ^ (r & 7);  // inverse-swizzled source chunk
            int ga = bm + r; if (ga >= M) ga = M - 1;
            __builtin_amdgcn_global_load_lds(
                (const __attribute__((address_space(1))) unsigned*)&A[(size_t)ga * K + k0 + c * 8],
                (__attribute__((address_space(3))) unsigned*)&As[fc * 8], 16, 0, 0);
            __builtin_amdgcn_global_load_lds(
                (const __attribute__((address_space(1))) unsigned*)&Bt[(size_t)(bn + r) * K + k0 + c * 8],
                (__attribute__((address_space(3))) unsigned*)&Bs[fc * 8], 16, 0, 0);
        }
        __syncthreads();             // staging visible (compiler drains vmcnt)

#pragma unroll
        for (int s = 0; s < 2; ++s) {
            const int kc = s * 4 + (lane >> 4);     // k-chunk index 0..7
            bf16x8 a[4], b[4];
#pragma unroll
            for (int m = 0; m < 4; ++m) {
                int row = wr * 64 + m * 16 + (lane & 15);
                int ch  = kc ^ (row & 7);
                a[m] = *(const bf16x8*)&As[row * BK + ch * 8];
            }
#pragma unroll
            for (int n = 0; n < 4; ++n) {
                int cl = wc * 64 + n * 16 + (lane & 15);
                int ch = kc ^ (cl & 7);
                b[n] = *(const bf16x8*)&Bs[cl * BK + ch * 8];
            }
#pragma unroll
            for (int m = 0; m < 4; ++m)
#pragma unroll
                for (int n = 0; n < 4; ++n)
                    acc[m][n] = __builtin_amdgcn_mfma_f32_16x16x32_bf16(a[m], b[n], acc[m][n], 0, 0, 0);
        }
    }

    // C/D layout: col = lane&15, row = (lane>>4)*4 + j   [m89-verified]
#pragma unroll
    for (int m = 0; m < 4; ++m) {
        int row0 = bm + wr * 64 + m * 16 + (lane >> 4) * 4;
#pragma unroll
        for (int n = 0; n < 4; ++n) {
            int coln = bn + wc * 64 + n * 16 + (lane & 15);
#pragma unroll
            for (int j = 0; j < 4; ++j) {
                int row = row0 + j;
                if (row < M) C[(size_t)row * HID + coln] = bf16r(acc[m][n][j]);
            }
        }
    }
}

// ---------------- per-node attention scalars (bf16 proj) ----------------

__global__ __launch_bounds__(256) void k_edotv(const ushort* __restrict__ proj,
                                               const float* __restrict__ asrc,
                                               const float* __restrict__ adst,
                                               float* __restrict__ esrc,
                                               float* __restrict__ edst) {
    int n = blockIdx.x;
    int t = threadIdx.x;
    ushort4 pv = *(const ushort4*)&proj[(size_t)n * HID + t * 4];
    float4 p  = make_float4(bf16f(pv.x), bf16f(pv.y), bf16f(pv.z), bf16f(pv.w));
    float4 as = *(const float4*)&asrc[t * 4];
    float4 ad = *(const float4*)&adst[t * 4];
    float ds_ = p.x * as.x + p.y * as.y + p.z * as.z + p.w * as.w;
    float dd  = p.x * ad.x + p.y * ad.y + p.z * ad.z + p.w * ad.w;
#pragma unroll
    for (int off = 32; off > 0; off >>= 1) {
        ds_ += __shfl_down(ds_, off);
        dd  += __shfl_down(dd, off);
    }
    if ((t & 63) == 0) {
        esrc[n * NHEADS + (t >> 6)] = ds_;
        edst[n * NHEADS + (t >> 6)] = dd;
    }
}

// ---------------- aggregation (softmax over incoming edges + weighted sum) ----------------

__global__ __launch_bounds__(256) void k_agg(const ushort* __restrict__ proj,
                                             const float* __restrict__ esrc,
                                             const float* __restrict__ edst,
                                             const int* __restrict__ row_ptr,
                                             const int* __restrict__ col,
                                             const float* __restrict__ bias,
                                             ushort* __restrict__ hb16) {
    int n = blockIdx.x;
    int t = threadIdx.x;
    int beg = row_ptr[n], end = row_ptr[n + 1];

    __shared__ float s_m[NHEADS], s_inv[NHEADS];

    if (t < 64) {
        float ed0 = edst[n * 4 + 0], ed1 = edst[n * 4 + 1];
        float ed2 = edst[n * 4 + 2], ed3 = edst[n * 4 + 3];
        float m0 = -1e30f, m1 = -1e30f, m2 = -1e30f, m3 = -1e30f;
        for (int j = beg + t; j < end; j += 64) {
            int s = col[j];
            float e0 = esrc[s * 4 + 0] + ed0; e0 = e0 > 0.f ? e0 : 0.2f * e0;
            float e1 = esrc[s * 4 + 1] + ed1; e1 = e1 > 0.f ? e1 : 0.2f * e1;
            float e2 = esrc[s * 4 + 2] + ed2; e2 = e2 > 0.f ? e2 : 0.2f * e2;
            float e3 = esrc[s * 4 + 3] + ed3; e3 = e3 > 0.f ? e3 : 0.2f * e3;
            m0 = fmaxf(m0, e0); m1 = fmaxf(m1, e1);
            m2 = fmaxf(m2, e2); m3 = fmaxf(m3, e3);
        }
#pragma unroll
        for (int off = 32; off > 0; off >>= 1) {
            m0 = fmaxf(m0, __shfl_xor(m0, off));
            m1 = fmaxf(m1, __shfl_xor(m1, off));
            m2 = fmaxf(m2, __shfl_xor(m2, off));
            m3 = fmaxf(m3, __shfl_xor(m3, off));
        }
        float d0 = 0.f, d1 = 0.f, d2 = 0.f, d3 = 0.f;
        for (int j = beg + t; j < end; j += 64) {
            int s = col[j];
            float e0 = esrc[s * 4 + 0] + ed0; e0 = e0 > 0.f ? e0 : 0.2f * e0;
            float e1 = esrc[s * 4 + 1] + ed1; e1 = e1 > 0.f ? e1 : 0.2f * e1;
            float e2 = esrc[s * 4 + 2] + ed2; e2 = e2 > 0.f ? e2 : 0.2f * e2;
            float e3 = esrc[s * 4 + 3] + ed3; e3 = e3 > 0.f ? e3 : 0.2f * e3;
            d0 += __expf(e0 - m0); d1 += __expf(e1 - m1);
            d2 += __expf(e2 - m2); d3 += __expf(e3 - m3);
        }
#pragma unroll
        for (int off = 32; off > 0; off >>= 1) {
            d0 += __shfl_xor(d0, off); d1 += __shfl_xor(d1, off);
            d2 += __shfl_xor(d2, off); d3 += __shfl_xor(d3, off);
        }
        if (t == 0) {
            s_m[0] = m0; s_m[1] = m1; s_m[2] = m2; s_m[3] = m3;
            s_inv[0] = 1.f / d0; s_inv[1] = 1.f / d1;
            s_inv[2] = 1.f / d2; s_inv[3] = 1.f / d3;
        }
    }
    __syncthreads();

    int h = t >> 6;
    float m = s_m[h], inv = s_inv[h];
    float edn = edst[n * 4 + h];
    float ax = 0.f, ay = 0.f, az = 0.f, aw = 0.f;
    for (int j = beg; j < end; ++j) {
        int s = col[j];
        float e = esrc[s * 4 + h] + edn;
        e = e > 0.f ? e : 0.2f * e;
        float alpha = __expf(e - m) * inv;
        ushort4 v = *(const ushort4*)&proj[(size_t)s * HID + t * 4];
        ax += alpha * bf16f(v.x); ay += alpha * bf16f(v.y);
        az += alpha * bf16f(v.z); aw += alpha * bf16f(v.w);
    }
    float4 b = *(const float4*)&bias[t * 4];
    ushort4 o;
    o.x = bf16r(fmaxf(ax + b.x, 0.f));
    o.y = bf16r(fmaxf(ay + b.y, 0.f));
    o.z = bf16r(fmaxf(az + b.z, 0.f));
    o.w = bf16r(fmaxf(aw + b.w, 0.f));
    *(ushort4*)&hb16[(size_t)n * HID + t * 4] = o;
}

// ---------------- pooling + FC + log_softmax ----------------

__global__ void k_bounds(const int* __restrict__ batch, int* __restrict__ gstart,
                         int* __restrict__ gend, int N) {
    int n = blockIdx.x * 256 + threadIdx.x;
    if (n < N) {
        int g = batch[n];
        if (n == 0 || batch[n - 1] != g) gstart[g] = n;
        if (n == N - 1 || batch[n + 1] != g) gend[g] = n + 1;
    }
}

// parallel pooling: node chunks x channel chunks, per-graph register accum,
// one f32 atomicAdd per graph-boundary per thread. pooled holds SUMS.
#define PCHUNK 32
__global__ __launch_bounds__(256) void k_pool(const ushort* __restrict__ h,
                                              const int* __restrict__ batch,
                                              float* __restrict__ pooled, int N) {
    int c  = blockIdx.y * 256 + threadIdx.x;
    int n0 = blockIdx.x * PCHUNK;
    int n1 = n0 + PCHUNK; if (n1 > N) n1 = N;
    int g = batch[n0];
    float acc = 0.f;
    for (int n = n0; n < n1; ++n) {
        int gn = batch[n];
        if (gn != g) {
            atomicAdd(&pooled[g * HID + c], acc);
            acc = 0.f; g = gn;
        }
        acc += bf16f(h[(size_t)n * HID + c]);
    }
    atomicAdd(&pooled[g * HID + c], acc);
}

__global__ __launch_bounds__(256) void k_fc(const float* __restrict__ pooled,
                                            const int* __restrict__ gstart,
                                            const int* __restrict__ gend,
                                            const float* __restrict__ fcw,
                                            const float* __restrict__ fcb,
                                            float* __restrict__ out) {
    int g = blockIdx.x;
    int t = threadIdx.x;
    float invc = 1.f / fmaxf((float)(gend[g] - gstart[g]), 1.f);
    __shared__ float red[NCLS][256];
    float part[NCLS];
#pragma unroll
    for (int c = 0; c < NCLS; ++c) part[c] = 0.f;
    for (int k = t; k < HID; k += 256) {
        float v = pooled[g * HID + k] * invc;
#pragma unroll
        for (int c = 0; c < NCLS; ++c) part[c] += v * fcw[k * NCLS + c];
    }
#pragma unroll
    for (int c = 0; c < NCLS; ++c) red[c][t] = part[c];
    __syncthreads();
    for (int off = 128; off > 0; off >>= 1) {
        if (t < off) {
#pragma unroll
            for (int c = 0; c < NCLS; ++c) red[c][t] += red[c][t + off];
        }
        __syncthreads();
    }
    if (t == 0) {
        float logits[NCLS];
        float mx = -1e30f;
#pragma unroll
        for (int c = 0; c < NCLS; ++c) {
            logits[c] = red[c][0] + fcb[c];
            mx = fmaxf(mx, logits[c]);
        }
        float se = 0.f;
#pragma unroll
        for (int c = 0; c < NCLS; ++c) se += expf(logits[c] - mx);
        float lse = mx + logf(se);
#pragma unroll
        for (int c = 0; c < NCLS; ++c) out[g * NCLS + c] = logits[c] - lse;
    }
}

// ---------------- launch ----------------

extern "C" void kernel_launch(void* const* d_in, const int* in_sizes, int n_in,
                              void* d_out, int out_size, void* d_ws, size_t ws_size,
                              hipStream_t stream) {
    const float* x    = (const float*)d_in[0];
    const int*   ei   = (const int*)d_in[1];
    const int*   batch= (const int*)d_in[2];
    const float* W0   = (const float*)d_in[3];
    const float* W1   = (const float*)d_in[4];
    const float* W2   = (const float*)d_in[5];
    const float* asrc = (const float*)d_in[6];
    const float* adst = (const float*)d_in[7];
    const float* bias = (const float*)d_in[8];
    const float* fcw  = (const float*)d_in[9];
    const float* fcb  = (const float*)d_in[10];
    float* out = (float*)d_out;

    const int E = in_sizes[1] / 2;
    const int N = NNODES;
    const int NE = E + N;

    // workspace layout
    char* ws = (char*)d_ws;
    size_t off = 0;
    auto alloc = [&](size_t bytes) { void* p = ws + off; off += (bytes + 255) & ~(size_t)255; return p; };
    ushort* projb  = (ushort*)alloc((size_t)N * HID * 2);       // GEMM output (bf16)
    ushort* hb16   = (ushort*)alloc((size_t)N * HID * 2);       // layer output (bf16)
    ushort* xb16   = (ushort*)alloc((size_t)N * 512 * 2);
    ushort* w0t    = (ushort*)alloc((size_t)HID * 512 * 2);
    ushort* w1t    = (ushort*)alloc((size_t)HID * HID * 2);
    ushort* w2t    = (ushort*)alloc((size_t)HID * HID * 2);
    float*  esrc   = (float*)alloc((size_t)N * NHEADS * 4);
    float*  edst   = (float*)alloc((size_t)N * NHEADS * 4);
    int*    counts = (int*)alloc((size_t)N * 4);
    int*    row_ptr= (int*)alloc((size_t)(N + 1) * 4);
    int*    fill   = (int*)alloc((size_t)N * 4);
    int*    col    = (int*)alloc((size_t)NE * 4);
    int*    gstart = (int*)alloc(NGRAPH * 4);
    int*    gend   = (int*)alloc(NGRAPH * 4);
    float*  pooled = (float*)alloc(NGRAPH * HID * 4);
    (void)ws_size;

    const int* srcArr = ei;
    const int* dstArr = ei + E;

    // CSR build
    hipMemsetAsync(counts, 0, (size_t)N * 4, stream);
    hipMemsetAsync(fill,   0, (size_t)N * 4, stream);
    hipMemsetAsync(gstart, 0, NGRAPH * 4, stream);
    hipMemsetAsync(gend,   0, NGRAPH * 4, stream);
    hipMemsetAsync(pooled, 0, NGRAPH * HID * 4, stream);
    int nbE = (NE + 255) / 256;
    k_hist<<<nbE, 256, 0, stream>>>(dstArr, counts, E);
    k_scan<<<1, 1024, 0, stream>>>(counts, row_ptr, N);
    k_scatter<<<nbE, 256, 0, stream>>>(srcArr, dstArr, row_ptr, fill, col, E);

    // conversions
    k_f32_to_bf16<<<(N * 512 / 4 + 255) / 256, 256, 0, stream>>>(x, xb16, N * 512 / 4);
    k_wT<<<dim3(32, 512 / 32), 256, 0, stream>>>(W0, w0t, 512);
    k_wT<<<dim3(32, HID / 32), 256, 0, stream>>>(W1, w1t, HID);
    k_wT<<<dim3(32, HID / 32), 256, 0, stream>>>(W2, w2t, HID);

    dim3 gemmGrid(HID / BN, (N + BM - 1) / BM);

    // layer 0
    k_gemm_bf16<<<gemmGrid, 256, 0, stream>>>(xb16, w0t, projb, N, 512);
    k_edotv<<<N, 256, 0, stream>>>(projb, asrc + 0 * HID, adst + 0 * HID, esrc, edst);
    k_agg<<<N, 256, 0, stream>>>(projb, esrc, edst, row_ptr, col, bias + 0 * HID, hb16);

    // layer 1
    k_gemm_bf16<<<gemmGrid, 256, 0, stream>>>(hb16, w1t, projb, N, HID);
    k_edotv<<<N, 256, 0, stream>>>(projb, asrc + 1 * HID, adst + 1 * HID, esrc, edst);
    k_agg<<<N, 256, 0, stream>>>(projb, esrc, edst, row_ptr, col, bias + 1 * HID, hb16);

    // layer 2
    k_gemm_bf16<<<gemmGrid, 256, 0, stream>>>(hb16, w2t, projb, N, HID);
    k_edotv<<<N, 256, 0, stream>>>(projb, asrc + 2 * HID, adst + 2 * HID, esrc, edst);
    k_agg<<<N, 256, 0, stream>>>(projb, esrc, edst, row_ptr, col, bias + 2 * HID, hb16);

    // pool + FC + log_softmax
    k_bounds<<<(N + 255) / 256, 256, 0, stream>>>(batch, gstart, gend, N);
    dim3 poolGrid((N + PCHUNK - 1) / PCHUNK, HID / 256);
    k_pool<<<poolGrid, 256, 0, stream>>>(hb16, batch, pooled, N);
    k_fc<<<NGRAPH, 256, 0, stream>>>(pooled, gstart, gend, fcw, fcb, out);
}

// Round 4
// 361.535 us; speedup vs baseline: 3.6081x; 1.0164x over previous
//
#include <hip/hip_runtime.h>
#include <math.h>

#define NNODES 10000
#define HID    1024
#define NHEADS 4
#define NGRAPH 16
#define NCLS   10

typedef __attribute__((ext_vector_type(8))) short bf16x8;
typedef __attribute__((ext_vector_type(8))) ushort u16x8;
typedef __attribute__((ext_vector_type(4))) float f32x4;

__device__ __forceinline__ ushort bf16r(float f) {
    union { float f; unsigned u; } x; x.f = f;
    unsigned r = x.u + 0x7FFFu + ((x.u >> 16) & 1u);
    return (ushort)(r >> 16);
}
__device__ __forceinline__ float bf16f(ushort u) {
    union { unsigned u; float f; } x; x.u = ((unsigned)u) << 16;
    return x.f;
}

// ---------------- CSR build ----------------

__global__ void k_hist(const int* __restrict__ dstArr, int* __restrict__ counts, int E) {
    int e = blockIdx.x * 256 + threadIdx.x;
    int total = E + NNODES;
    if (e < total) {
        int d = (e < E) ? dstArr[e] : (e - E);   // self-loops appended
        atomicAdd(&counts[d], 1);
    }
}

__global__ __launch_bounds__(1024) void k_scan(const int* __restrict__ counts,
                                               int* __restrict__ row_ptr, int N) {
    __shared__ int lds[1024];
    int t = threadIdx.x;
    const int C = (N + 1023) / 1024;
    int base = t * C;
    int s = 0;
    for (int i = 0; i < C; ++i)
        if (base + i < N) s += counts[base + i];
    lds[t] = s;
    __syncthreads();
    for (int off = 1; off < 1024; off <<= 1) {
        int add = (t >= off) ? lds[t - off] : 0;
        __syncthreads();
        lds[t] += add;
        __syncthreads();
    }
    int run = lds[t] - s;   // exclusive prefix
    for (int i = 0; i < C; ++i) {
        if (base + i < N) {
            row_ptr[base + i] = run;
            run += counts[base + i];
        }
    }
    if (t == 1023) row_ptr[N] = lds[1023];
}

__global__ void k_scatter(const int* __restrict__ srcArr, const int* __restrict__ dstArr,
                          const int* __restrict__ row_ptr, int* __restrict__ fill,
                          int* __restrict__ col, int E) {
    int e = blockIdx.x * 256 + threadIdx.x;
    int total = E + NNODES;
    if (e < total) {
        int s, d;
        if (e < E) { s = srcArr[e]; d = dstArr[e]; }
        else       { s = d = e - E; }
        int pos = row_ptr[d] + atomicAdd(&fill[d], 1);
        col[pos] = s;
    }
}

// ---------------- conversions ----------------

__global__ void k_f32_to_bf16(const float* __restrict__ in, ushort* __restrict__ out, int n4) {
    int i = blockIdx.x * 256 + threadIdx.x;
    if (i < n4) {
        float4 v = ((const float4*)in)[i];
        ushort4 o;
        o.x = bf16r(v.x); o.y = bf16r(v.y); o.z = bf16r(v.z); o.w = bf16r(v.w);
        ((ushort4*)out)[i] = o;
    }
}

// W [K][1024] f32 -> Wt [1024][K] bf16
__global__ __launch_bounds__(256) void k_wT(const float* __restrict__ W, ushort* __restrict__ Wt, int K) {
    __shared__ ushort tile[32][33];
    int bx = blockIdx.x;              // along N (1024/32)
    int by = blockIdx.y;              // along K
    int tx = threadIdx.x & 31, ty = threadIdx.x >> 5;   // 32 x 8
#pragma unroll
    for (int i = 0; i < 32; i += 8) {
        int k  = by * 32 + ty + i;
        int nn = bx * 32 + tx;
        tile[ty + i][tx] = bf16r(W[(size_t)k * HID + nn]);
    }
    __syncthreads();
#pragma unroll
    for (int i = 0; i < 32; i += 8) {
        int nn = bx * 32 + ty + i;
        int k  = by * 32 + tx;
        Wt[(size_t)nn * K + k] = tile[tx][ty + i];
    }
}

// ---------------- bf16 MFMA GEMM: C[M,1024] = A[M,K] * Bt[1024,K]^T, bf16 out ----------------

#define BM 128
#define BN 128
#define BK 64

__global__ __launch_bounds__(256) void k_gemm_bf16(const ushort* __restrict__ A,
                                                   const ushort* __restrict__ Bt,
                                                   ushort* __restrict__ C, int M, int K) {
    __shared__ ushort As[BM * BK];
    __shared__ ushort Bs[BN * BK];
    const int t    = threadIdx.x;
    const int lane = t & 63;
    const int w    = t >> 6;
    const int wr   = w >> 1, wc = w & 1;
    const int bm   = blockIdx.y * BM;
    const int bn   = blockIdx.x * BN;

    f32x4 acc[4][4] = {};

    const int r_  = t >> 3;          // fc = i*256+t -> row = i*32 + t>>3
    const int cp_ = t & 7;           // linear chunk within row

    for (int k0 = 0; k0 < K; k0 += BK) {
        __syncthreads();             // LDS free for overwrite
#pragma unroll
        for (int i = 0; i < 4; ++i) {
            int fc = i * 256 + t;
            int r  = i * 32 + r_;
            int c  = cp_ ^ (r & 7);  // inverse-swizzled source chunk
            int ga = bm + r; if (ga >= M) ga = M - 1;
            __builtin_amdgcn_global_load_lds(
                (const __attribute__((address_space(1))) unsigned*)&A[(size_t)ga * K + k0 + c * 8],
                (__attribute__((address_space(3))) unsigned*)&As[fc * 8], 16, 0, 0);
            __builtin_amdgcn_global_load_lds(
                (const __attribute__((address_space(1))) unsigned*)&Bt[(size_t)(bn + r) * K + k0 + c * 8],
                (__attribute__((address_space(3))) unsigned*)&Bs[fc * 8], 16, 0, 0);
        }
        __syncthreads();             // staging visible (compiler drains vmcnt)

#pragma unroll
        for (int s = 0; s < 2; ++s) {
            const int kc = s * 4 + (lane >> 4);     // k-chunk index 0..7
            bf16x8 a[4], b[4];
#pragma unroll
            for (int m = 0; m < 4; ++m) {
                int row = wr * 64 + m * 16 + (lane & 15);
                int ch  = kc ^ (row & 7);
                a[m] = *(const bf16x8*)&As[row * BK + ch * 8];
            }
#pragma unroll
            for (int n = 0; n < 4; ++n) {
                int cl = wc * 64 + n * 16 + (lane & 15);
                int ch = kc ^ (cl & 7);
                b[n] = *(const bf16x8*)&Bs[cl * BK + ch * 8];
            }
#pragma unroll
            for (int m = 0; m < 4; ++m)
#pragma unroll
                for (int n = 0; n < 4; ++n)
                    acc[m][n] = __builtin_amdgcn_mfma_f32_16x16x32_bf16(a[m], b[n], acc[m][n], 0, 0, 0);
        }
    }

    // C/D layout: col = lane&15, row = (lane>>4)*4 + j   [m89-verified]
#pragma unroll
    for (int m = 0; m < 4; ++m) {
        int row0 = bm + wr * 64 + m * 16 + (lane >> 4) * 4;
#pragma unroll
        for (int n = 0; n < 4; ++n) {
            int coln = bn + wc * 64 + n * 16 + (lane & 15);
#pragma unroll
            for (int j = 0; j < 4; ++j) {
                int row = row0 + j;
                if (row < M) C[(size_t)row * HID + coln] = bf16r(acc[m][n][j]);
            }
        }
    }
}

// ---------------- per-node attention scalars (bf16 proj) ----------------
// 1 wave per node, 4 nodes per block. lane covers 16 channels (32B).

__global__ __launch_bounds__(256) void k_edotv(const ushort* __restrict__ proj,
                                               const float* __restrict__ asrc,
                                               const float* __restrict__ adst,
                                               float* __restrict__ esrc,
                                               float* __restrict__ edst) {
    int lane = threadIdx.x & 63;
    int n = blockIdx.x * 4 + (threadIdx.x >> 6);
    int h = lane >> 4;                 // 16 lanes per head
    int c0 = lane * 16;
    u16x8 p0 = *(const u16x8*)&proj[(size_t)n * HID + c0];
    u16x8 p1 = *(const u16x8*)&proj[(size_t)n * HID + c0 + 8];
    float ds_ = 0.f, dd = 0.f;
#pragma unroll
    for (int i = 0; i < 8; ++i) {
        float v0 = bf16f(p0[i]), v1 = bf16f(p1[i]);
        ds_ += v0 * asrc[c0 + i] + v1 * asrc[c0 + 8 + i];
        dd  += v0 * adst[c0 + i] + v1 * adst[c0 + 8 + i];
    }
#pragma unroll
    for (int off = 8; off > 0; off >>= 1) {
        ds_ += __shfl_xor(ds_, off);
        dd  += __shfl_xor(dd, off);
    }
    if ((lane & 15) == 0) {
        esrc[n * NHEADS + h] = ds_;
        edst[n * NHEADS + h] = dd;
    }
}

// ---------------- aggregation (softmax over incoming edges + weighted sum) ----------------
// 2 waves per node (128 threads x 8 ch = 1024), 2 nodes per 256-block.
// Phase 1: per-head 32-lane-group max/denom. Phase 2: 16B/lane row gather.

__global__ __launch_bounds__(256) void k_agg(const ushort* __restrict__ proj,
                                             const float* __restrict__ esrc,
                                             const float* __restrict__ edst,
                                             const int* __restrict__ row_ptr,
                                             const int* __restrict__ col,
                                             const float* __restrict__ bias,
                                             ushort* __restrict__ hb16) {
    const int half = threadIdx.x >> 7;             // which node of the pair
    const int nid  = blockIdx.x * 2 + half;
    const int tt   = threadIdx.x & 127;
    const int h    = tt >> 5;                      // head (channels tt*8 span head tt>>5)
    const int beg  = row_ptr[nid], end = row_ptr[nid + 1];
    const float edn = edst[nid * 4 + h];

    __shared__ float s_m[2][NHEADS], s_inv[2][NHEADS];

    // phase 1: max + denom, 32 lanes per head
    {
        const int l = tt & 31;
        float m = -1e30f;
        for (int j = beg + l; j < end; j += 32) {
            int s = col[j];
            float e = esrc[s * 4 + h] + edn;
            e = e > 0.f ? e : 0.2f * e;
            m = fmaxf(m, e);
        }
#pragma unroll
        for (int off = 16; off > 0; off >>= 1) m = fmaxf(m, __shfl_xor(m, off));
        float d = 0.f;
        for (int j = beg + l; j < end; j += 32) {
            int s = col[j];
            float e = esrc[s * 4 + h] + edn;
            e = e > 0.f ? e : 0.2f * e;
            d += __expf(e - m);
        }
#pragma unroll
        for (int off = 16; off > 0; off >>= 1) d += __shfl_xor(d, off);
        if (l == 0) { s_m[half][h] = m; s_inv[half][h] = 1.f / d; }
    }
    __syncthreads();

    const float m  = s_m[half][h];
    const float inv = s_inv[half][h];
    float acc[8] = {};
    for (int j = beg; j < end; ++j) {
        int s = col[j];
        float e = esrc[s * 4 + h] + edn;
        e = e > 0.f ? e : 0.2f * e;
        float alpha = __expf(e - m) * inv;
        u16x8 v = *(const u16x8*)&proj[(size_t)s * HID + tt * 8];
#pragma unroll
        for (int i = 0; i < 8; ++i) acc[i] += alpha * bf16f(v[i]);
    }
    u16x8 o;
#pragma unroll
    for (int i = 0; i < 8; ++i) {
        float b = bias[tt * 8 + i];
        o[i] = bf16r(fmaxf(acc[i] + b, 0.f));
    }
    *(u16x8*)&hb16[(size_t)nid * HID + tt * 8] = o;
}

// ---------------- pooling + FC + log_softmax ----------------

__global__ void k_bounds(const int* __restrict__ batch, int* __restrict__ gstart,
                         int* __restrict__ gend, int N) {
    int n = blockIdx.x * 256 + threadIdx.x;
    if (n < N) {
        int g = batch[n];
        if (n == 0 || batch[n - 1] != g) gstart[g] = n;
        if (n == N - 1 || batch[n + 1] != g) gend[g] = n + 1;
    }
}

// parallel pooling: node chunks x channel chunks, per-graph register accum,
// one f32 atomicAdd per graph-boundary per thread. pooled holds SUMS.
#define PCHUNK 32
__global__ __launch_bounds__(256) void k_pool(const ushort* __restrict__ h,
                                              const int* __restrict__ batch,
                                              float* __restrict__ pooled, int N) {
    int c  = blockIdx.y * 256 + threadIdx.x;
    int n0 = blockIdx.x * PCHUNK;
    int n1 = n0 + PCHUNK; if (n1 > N) n1 = N;
    int g = batch[n0];
    float acc = 0.f;
    for (int n = n0; n < n1; ++n) {
        int gn = batch[n];
        if (gn != g) {
            atomicAdd(&pooled[g * HID + c], acc);
            acc = 0.f; g = gn;
        }
        acc += bf16f(h[(size_t)n * HID + c]);
    }
    atomicAdd(&pooled[g * HID + c], acc);
}

__global__ __launch_bounds__(256) void k_fc(const float* __restrict__ pooled,
                                            const int* __restrict__ gstart,
                                            const int* __restrict__ gend,
                                            const float* __restrict__ fcw,
                                            const float* __restrict__ fcb,
                                            float* __restrict__ out) {
    int g = blockIdx.x;
    int t = threadIdx.x;
    float invc = 1.f / fmaxf((float)(gend[g] - gstart[g]), 1.f);
    __shared__ float red[NCLS][256];
    float part[NCLS];
#pragma unroll
    for (int c = 0; c < NCLS; ++c) part[c] = 0.f;
    for (int k = t; k < HID; k += 256) {
        float v = pooled[g * HID + k] * invc;
#pragma unroll
        for (int c = 0; c < NCLS; ++c) part[c] += v * fcw[k * NCLS + c];
    }
#pragma unroll
    for (int c = 0; c < NCLS; ++c) red[c][t] = part[c];
    __syncthreads();
    for (int off = 128; off > 0; off >>= 1) {
        if (t < off) {
#pragma unroll
            for (int c = 0; c < NCLS; ++c) red[c][t] += red[c][t + off];
        }
        __syncthreads();
    }
    if (t == 0) {
        float logits[NCLS];
        float mx = -1e30f;
#pragma unroll
        for (int c = 0; c < NCLS; ++c) {
            logits[c] = red[c][0] + fcb[c];
            mx = fmaxf(mx, logits[c]);
        }
        float se = 0.f;
#pragma unroll
        for (int c = 0; c < NCLS; ++c) se += expf(logits[c] - mx);
        float lse = mx + logf(se);
#pragma unroll
        for (int c = 0; c < NCLS; ++c) out[g * NCLS + c] = logits[c] - lse;
    }
}

// ---------------- launch ----------------

extern "C" void kernel_launch(void* const* d_in, const int* in_sizes, int n_in,
                              void* d_out, int out_size, void* d_ws, size_t ws_size,
                              hipStream_t stream) {
    const float* x    = (const float*)d_in[0];
    const int*   ei   = (const int*)d_in[1];
    const int*   batch= (const int*)d_in[2];
    const float* W0   = (const float*)d_in[3];
    const float* W1   = (const float*)d_in[4];
    const float* W2   = (const float*)d_in[5];
    const float* asrc = (const float*)d_in[6];
    const float* adst = (const float*)d_in[7];
    const float* bias = (const float*)d_in[8];
    const float* fcw  = (const float*)d_in[9];
    const float* fcb  = (const float*)d_in[10];
    float* out = (float*)d_out;

    const int E = in_sizes[1] / 2;
    const int N = NNODES;
    const int NE = E + N;

    // workspace layout
    char* ws = (char*)d_ws;
    size_t off = 0;
    auto alloc = [&](size_t bytes) { void* p = ws + off; off += (bytes + 255) & ~(size_t)255; return p; };
    ushort* projb  = (ushort*)alloc((size_t)N * HID * 2);       // GEMM output (bf16)
    ushort* hb16   = (ushort*)alloc((size_t)N * HID * 2);       // layer output (bf16)
    ushort* xb16   = (ushort*)alloc((size_t)N * 512 * 2);
    ushort* w0t    = (ushort*)alloc((size_t)HID * 512 * 2);
    ushort* w1t    = (ushort*)alloc((size_t)HID * HID * 2);
    ushort* w2t    = (ushort*)alloc((size_t)HID * HID * 2);
    float*  esrc   = (float*)alloc((size_t)N * NHEADS * 4);
    float*  edst   = (float*)alloc((size_t)N * NHEADS * 4);
    int*    counts = (int*)alloc((size_t)N * 4);
    int*    row_ptr= (int*)alloc((size_t)(N + 1) * 4);
    int*    fill   = (int*)alloc((size_t)N * 4);
    int*    col    = (int*)alloc((size_t)NE * 4);
    int*    gstart = (int*)alloc(NGRAPH * 4);
    int*    gend   = (int*)alloc(NGRAPH * 4);
    float*  pooled = (float*)alloc(NGRAPH * HID * 4);
    (void)ws_size;

    const int* srcArr = ei;
    const int* dstArr = ei + E;

    // CSR build
    hipMemsetAsync(counts, 0, (size_t)N * 4, stream);
    hipMemsetAsync(fill,   0, (size_t)N * 4, stream);
    hipMemsetAsync(gstart, 0, NGRAPH * 4, stream);
    hipMemsetAsync(gend,   0, NGRAPH * 4, stream);
    hipMemsetAsync(pooled, 0, NGRAPH * HID * 4, stream);
    int nbE = (NE + 255) / 256;
    k_hist<<<nbE, 256, 0, stream>>>(dstArr, counts, E);
    k_scan<<<1, 1024, 0, stream>>>(counts, row_ptr, N);
    k_scatter<<<nbE, 256, 0, stream>>>(srcArr, dstArr, row_ptr, fill, col, E);

    // conversions
    k_f32_to_bf16<<<(N * 512 / 4 + 255) / 256, 256, 0, stream>>>(x, xb16, N * 512 / 4);
    k_wT<<<dim3(32, 512 / 32), 256, 0, stream>>>(W0, w0t, 512);
    k_wT<<<dim3(32, HID / 32), 256, 0, stream>>>(W1, w1t, HID);
    k_wT<<<dim3(32, HID / 32), 256, 0, stream>>>(W2, w2t, HID);

    dim3 gemmGrid(HID / BN, (N + BM - 1) / BM);

    // layer 0
    k_gemm_bf16<<<gemmGrid, 256, 0, stream>>>(xb16, w0t, projb, N, 512);
    k_edotv<<<N / 4, 256, 0, stream>>>(projb, asrc + 0 * HID, adst + 0 * HID, esrc, edst);
    k_agg<<<N / 2, 256, 0, stream>>>(projb, esrc, edst, row_ptr, col, bias + 0 * HID, hb16);

    // layer 1
    k_gemm_bf16<<<gemmGrid, 256, 0, stream>>>(hb16, w1t, projb, N, HID);
    k_edotv<<<N / 4, 256, 0, stream>>>(projb, asrc + 1 * HID, adst + 1 * HID, esrc, edst);
    k_agg<<<N / 2, 256, 0, stream>>>(projb, esrc, edst, row_ptr, col, bias + 1 * HID, hb16);

    // layer 2
    k_gemm_bf16<<<gemmGrid, 256, 0, stream>>>(hb16, w2t, projb, N, HID);
    k_edotv<<<N / 4, 256, 0, stream>>>(projb, asrc + 2 * HID, adst + 2 * HID, esrc, edst);
    k_agg<<<N / 2, 256, 0, stream>>>(projb, esrc, edst, row_ptr, col, bias + 2 * HID, hb16);

    // pool + FC + log_softmax
    k_bounds<<<(N + 255) / 256, 256, 0, stream>>>(batch, gstart, gend, N);
    dim3 poolGrid((N + PCHUNK - 1) / PCHUNK, HID / 256);
    k_pool<<<poolGrid, 256, 0, stream>>>(hb16, batch, pooled, N);
    k_fc<<<NGRAPH, 256, 0, stream>>>(pooled, gstart, gend, fcw, fcb, out);
}

// Round 5
// 352.200 us; speedup vs baseline: 3.7038x; 1.0265x over previous
//
#include <hip/hip_runtime.h>
#include <math.h>

#define NNODES 10000
#define HID    1024
#define NHEADS 4
#define NGRAPH 16
#define NCLS   10

typedef __attribute__((ext_vector_type(8))) short bf16x8;
typedef __attribute__((ext_vector_type(8))) ushort u16x8;
typedef __attribute__((ext_vector_type(4))) float f32x4;

__device__ __forceinline__ ushort bf16r(float f) {
    union { float f; unsigned u; } x; x.f = f;
    unsigned r = x.u + 0x7FFFu + ((x.u >> 16) & 1u);
    return (ushort)(r >> 16);
}
__device__ __forceinline__ float bf16f(ushort u) {
    union { unsigned u; float f; } x; x.u = ((unsigned)u) << 16;
    return x.f;
}
__device__ __forceinline__ float leaky(float e) { return e > 0.f ? e : 0.2f * e; }

// ---------------- CSR build ----------------

__global__ void k_hist(const int* __restrict__ dstArr, int* __restrict__ counts, int E) {
    int e = blockIdx.x * 256 + threadIdx.x;
    int total = E + NNODES;
    if (e < total) {
        int d = (e < E) ? dstArr[e] : (e - E);   // self-loops appended
        atomicAdd(&counts[d], 1);
    }
}

__global__ __launch_bounds__(1024) void k_scan(const int* __restrict__ counts,
                                               int* __restrict__ row_ptr, int N) {
    __shared__ int lds[1024];
    int t = threadIdx.x;
    const int C = (N + 1023) / 1024;
    int base = t * C;
    int s = 0;
    for (int i = 0; i < C; ++i)
        if (base + i < N) s += counts[base + i];
    lds[t] = s;
    __syncthreads();
    for (int off = 1; off < 1024; off <<= 1) {
        int add = (t >= off) ? lds[t - off] : 0;
        __syncthreads();
        lds[t] += add;
        __syncthreads();
    }
    int run = lds[t] - s;   // exclusive prefix
    for (int i = 0; i < C; ++i) {
        if (base + i < N) {
            row_ptr[base + i] = run;
            run += counts[base + i];
        }
    }
    if (t == 1023) row_ptr[N] = lds[1023];
}

__global__ void k_scatter(const int* __restrict__ srcArr, const int* __restrict__ dstArr,
                          const int* __restrict__ row_ptr, int* __restrict__ fill,
                          int* __restrict__ col, int E) {
    int e = blockIdx.x * 256 + threadIdx.x;
    int total = E + NNODES;
    if (e < total) {
        int s, d;
        if (e < E) { s = srcArr[e]; d = dstArr[e]; }
        else       { s = d = e - E; }
        int pos = row_ptr[d] + atomicAdd(&fill[d], 1);
        col[pos] = s;
    }
}

// ---------------- conversions ----------------

__global__ void k_f32_to_bf16(const float* __restrict__ in, ushort* __restrict__ out, int n4) {
    int i = blockIdx.x * 256 + threadIdx.x;
    if (i < n4) {
        float4 v = ((const float4*)in)[i];
        ushort4 o;
        o.x = bf16r(v.x); o.y = bf16r(v.y); o.z = bf16r(v.z); o.w = bf16r(v.w);
        ((ushort4*)out)[i] = o;
    }
}

// W [K][1024] f32 -> Wt [1024][K] bf16
__global__ __launch_bounds__(256) void k_wT(const float* __restrict__ W, ushort* __restrict__ Wt, int K) {
    __shared__ ushort tile[32][33];
    int bx = blockIdx.x;              // along N (1024/32)
    int by = blockIdx.y;              // along K
    int tx = threadIdx.x & 31, ty = threadIdx.x >> 5;   // 32 x 8
#pragma unroll
    for (int i = 0; i < 32; i += 8) {
        int k  = by * 32 + ty + i;
        int nn = bx * 32 + tx;
        tile[ty + i][tx] = bf16r(W[(size_t)k * HID + nn]);
    }
    __syncthreads();
#pragma unroll
    for (int i = 0; i < 32; i += 8) {
        int nn = bx * 32 + ty + i;
        int k  = by * 32 + tx;
        Wt[(size_t)nn * K + k] = tile[tx][ty + i];
    }
}

// ---------------- bf16 MFMA GEMM: C[M,1024] = A[M,K] * Bt[1024,K]^T, bf16 out ----------------

#define BM 128
#define BN 128
#define BK 64

__global__ __launch_bounds__(256) void k_gemm_bf16(const ushort* __restrict__ A,
                                                   const ushort* __restrict__ Bt,
                                                   ushort* __restrict__ C, int M, int K) {
    __shared__ ushort As[BM * BK];
    __shared__ ushort Bs[BN * BK];
    const int t    = threadIdx.x;
    const int lane = t & 63;
    const int w    = t >> 6;
    const int wr   = w >> 1, wc = w & 1;
    const int bm   = blockIdx.y * BM;
    const int bn   = blockIdx.x * BN;

    f32x4 acc[4][4] = {};

    const int r_  = t >> 3;          // fc = i*256+t -> row = i*32 + t>>3
    const int cp_ = t & 7;           // linear chunk within row

    for (int k0 = 0; k0 < K; k0 += BK) {
        __syncthreads();             // LDS free for overwrite
#pragma unroll
        for (int i = 0; i < 4; ++i) {
            int fc = i * 256 + t;
            int r  = i * 32 + r_;
            int c  = cp_ ^ (r & 7);  // inverse-swizzled source chunk
            int ga = bm + r; if (ga >= M) ga = M - 1;
            __builtin_amdgcn_global_load_lds(
                (const __attribute__((address_space(1))) unsigned*)&A[(size_t)ga * K + k0 + c * 8],
                (__attribute__((address_space(3))) unsigned*)&As[fc * 8], 16, 0, 0);
            __builtin_amdgcn_global_load_lds(
                (const __attribute__((address_space(1))) unsigned*)&Bt[(size_t)(bn + r) * K + k0 + c * 8],
                (__attribute__((address_space(3))) unsigned*)&Bs[fc * 8], 16, 0, 0);
        }
        __syncthreads();             // staging visible (compiler drains vmcnt)

#pragma unroll
        for (int s = 0; s < 2; ++s) {
            const int kc = s * 4 + (lane >> 4);     // k-chunk index 0..7
            bf16x8 a[4], b[4];
#pragma unroll
            for (int m = 0; m < 4; ++m) {
                int row = wr * 64 + m * 16 + (lane & 15);
                int ch  = kc ^ (row & 7);
                a[m] = *(const bf16x8*)&As[row * BK + ch * 8];
            }
#pragma unroll
            for (int n = 0; n < 4; ++n) {
                int cl = wc * 64 + n * 16 + (lane & 15);
                int ch = kc ^ (cl & 7);
                b[n] = *(const bf16x8*)&Bs[cl * BK + ch * 8];
            }
#pragma unroll
            for (int m = 0; m < 4; ++m)
#pragma unroll
                for (int n = 0; n < 4; ++n)
                    acc[m][n] = __builtin_amdgcn_mfma_f32_16x16x32_bf16(a[m], b[n], acc[m][n], 0, 0, 0);
        }
    }

    // C/D layout: col = lane&15, row = (lane>>4)*4 + j   [m89-verified]
#pragma unroll
    for (int m = 0; m < 4; ++m) {
        int row0 = bm + wr * 64 + m * 16 + (lane >> 4) * 4;
#pragma unroll
        for (int n = 0; n < 4; ++n) {
            int coln = bn + wc * 64 + n * 16 + (lane & 15);
#pragma unroll
            for (int j = 0; j < 4; ++j) {
                int row = row0 + j;
                if (row < M) C[(size_t)row * HID + coln] = bf16r(acc[m][n][j]);
            }
        }
    }
}

// ---------------- per-node attention scalars (bf16 proj) ----------------
// 1 wave per node, 4 nodes per block. lane covers 16 channels (32B).

__global__ __launch_bounds__(256) void k_edotv(const ushort* __restrict__ proj,
                                               const float* __restrict__ asrc,
                                               const float* __restrict__ adst,
                                               float* __restrict__ esrc,
                                               float* __restrict__ edst) {
    int lane = threadIdx.x & 63;
    int n = blockIdx.x * 4 + (threadIdx.x >> 6);
    int h = lane >> 4;                 // 16 lanes per head
    int c0 = lane * 16;
    u16x8 p0 = *(const u16x8*)&proj[(size_t)n * HID + c0];
    u16x8 p1 = *(const u16x8*)&proj[(size_t)n * HID + c0 + 8];
    float ds_ = 0.f, dd = 0.f;
#pragma unroll
    for (int i = 0; i < 8; ++i) {
        float v0 = bf16f(p0[i]), v1 = bf16f(p1[i]);
        ds_ += v0 * asrc[c0 + i] + v1 * asrc[c0 + 8 + i];
        dd  += v0 * adst[c0 + i] + v1 * adst[c0 + 8 + i];
    }
#pragma unroll
    for (int off = 8; off > 0; off >>= 1) {
        ds_ += __shfl_xor(ds_, off);
        dd  += __shfl_xor(dd, off);
    }
    if ((lane & 15) == 0) {
        esrc[n * NHEADS + h] = ds_;
        edst[n * NHEADS + h] = dd;
    }
}

// ---------------- per-edge normalized attention weights ----------------
// 1 wave per node, 4 nodes per block. Lane <-> CSR slot (strided if deg>64).
// One random 16B esrc load per edge TOTAL; all 4 heads in registers;
// shuffle-reduce max/denom; write alpha[j][4] contiguous.

__global__ __launch_bounds__(256) void k_alpha(const float* __restrict__ esrc,
                                               const float* __restrict__ edst,
                                               const int* __restrict__ row_ptr,
                                               const int* __restrict__ col,
                                               float* __restrict__ alpha) {
    const int lane = threadIdx.x & 63;
    const int n = blockIdx.x * 4 + (threadIdx.x >> 6);
    const int beg = row_ptr[n], end = row_ptr[n + 1];
    const int deg = end - beg;
    const float4 ed = *(const float4*)&edst[n * 4];

    // cached e for up to 2 strided slots (covers deg <= 128; more handled by recompute)
    float e0[4], e1[4];
    const bool has0 = lane < deg;
    const bool has1 = lane + 64 < deg;
    float m0 = -1e30f, m1 = -1e30f, m2 = -1e30f, m3 = -1e30f;
    if (has0) {
        float4 es = *(const float4*)&esrc[col[beg + lane] * 4];
        e0[0] = leaky(es.x + ed.x); e0[1] = leaky(es.y + ed.y);
        e0[2] = leaky(es.z + ed.z); e0[3] = leaky(es.w + ed.w);
        m0 = e0[0]; m1 = e0[1]; m2 = e0[2]; m3 = e0[3];
    }
    if (has1) {
        float4 es = *(const float4*)&esrc[col[beg + 64 + lane] * 4];
        e1[0] = leaky(es.x + ed.x); e1[1] = leaky(es.y + ed.y);
        e1[2] = leaky(es.z + ed.z); e1[3] = leaky(es.w + ed.w);
        m0 = fmaxf(m0, e1[0]); m1 = fmaxf(m1, e1[1]);
        m2 = fmaxf(m2, e1[2]); m3 = fmaxf(m3, e1[3]);
    }
    for (int j = beg + 128 + lane; j < end; j += 64) {   // rare path
        float4 es = *(const float4*)&esrc[col[j] * 4];
        m0 = fmaxf(m0, leaky(es.x + ed.x)); m1 = fmaxf(m1, leaky(es.y + ed.y));
        m2 = fmaxf(m2, leaky(es.z + ed.z)); m3 = fmaxf(m3, leaky(es.w + ed.w));
    }
#pragma unroll
    for (int off = 32; off > 0; off >>= 1) {
        m0 = fmaxf(m0, __shfl_xor(m0, off)); m1 = fmaxf(m1, __shfl_xor(m1, off));
        m2 = fmaxf(m2, __shfl_xor(m2, off)); m3 = fmaxf(m3, __shfl_xor(m3, off));
    }
    float d0 = 0.f, d1 = 0.f, d2 = 0.f, d3 = 0.f;
    if (has0) {
        e0[0] = __expf(e0[0] - m0); e0[1] = __expf(e0[1] - m1);
        e0[2] = __expf(e0[2] - m2); e0[3] = __expf(e0[3] - m3);
        d0 += e0[0]; d1 += e0[1]; d2 += e0[2]; d3 += e0[3];
    }
    if (has1) {
        e1[0] = __expf(e1[0] - m0); e1[1] = __expf(e1[1] - m1);
        e1[2] = __expf(e1[2] - m2); e1[3] = __expf(e1[3] - m3);
        d0 += e1[0]; d1 += e1[1]; d2 += e1[2]; d3 += e1[3];
    }
    for (int j = beg + 128 + lane; j < end; j += 64) {   // rare path
        float4 es = *(const float4*)&esrc[col[j] * 4];
        d0 += __expf(leaky(es.x + ed.x) - m0); d1 += __expf(leaky(es.y + ed.y) - m1);
        d2 += __expf(leaky(es.z + ed.z) - m2); d3 += __expf(leaky(es.w + ed.w) - m3);
    }
#pragma unroll
    for (int off = 32; off > 0; off >>= 1) {
        d0 += __shfl_xor(d0, off); d1 += __shfl_xor(d1, off);
        d2 += __shfl_xor(d2, off); d3 += __shfl_xor(d3, off);
    }
    const float i0 = 1.f / d0, i1 = 1.f / d1, i2 = 1.f / d2, i3 = 1.f / d3;
    if (has0) {
        float4 a = make_float4(e0[0] * i0, e0[1] * i1, e0[2] * i2, e0[3] * i3);
        *(float4*)&alpha[(size_t)(beg + lane) * 4] = a;
    }
    if (has1) {
        float4 a = make_float4(e1[0] * i0, e1[1] * i1, e1[2] * i2, e1[3] * i3);
        *(float4*)&alpha[(size_t)(beg + 64 + lane) * 4] = a;
    }
    for (int j = beg + 128 + lane; j < end; j += 64) {   // rare path
        float4 es = *(const float4*)&esrc[col[j] * 4];
        float4 a = make_float4(__expf(leaky(es.x + ed.x) - m0) * i0,
                               __expf(leaky(es.y + ed.y) - m1) * i1,
                               __expf(leaky(es.z + ed.z) - m2) * i2,
                               __expf(leaky(es.w + ed.w) - m3) * i3);
        *(float4*)&alpha[(size_t)j * 4] = a;
    }
}

// ---------------- aggregation: pure alpha-weighted gather ----------------
// 2 waves per node (128 threads x 8 ch = 1024), 2 nodes per 256-block.
// Depth-2 software prefetch on the random row gather.

__global__ __launch_bounds__(256) void k_agg(const ushort* __restrict__ proj,
                                             const float* __restrict__ alpha,
                                             const int* __restrict__ row_ptr,
                                             const int* __restrict__ col,
                                             const float* __restrict__ bias,
                                             ushort* __restrict__ hb16) {
    const int half = threadIdx.x >> 7;             // which node of the pair
    const int nid  = blockIdx.x * 2 + half;
    const int tt   = threadIdx.x & 127;
    const int h    = tt >> 5;                      // head (channels tt*8 span head tt>>5)
    const int beg  = row_ptr[nid], end = row_ptr[nid + 1];

    float acc[8] = {};
    // depth-2 pipeline (deg >= 1 guaranteed by self-loop)
    int j = beg;
    u16x8 v0, v1;
    float a0 = 0.f, a1 = 0.f;
    a0 = alpha[(size_t)j * 4 + h];
    v0 = *(const u16x8*)&proj[(size_t)col[j] * HID + tt * 8];
    if (j + 1 < end) {
        a1 = alpha[(size_t)(j + 1) * 4 + h];
        v1 = *(const u16x8*)&proj[(size_t)col[j + 1] * HID + tt * 8];
    }
    for (; j + 2 < end; ++j) {
        float a2 = alpha[(size_t)(j + 2) * 4 + h];
        u16x8 v2 = *(const u16x8*)&proj[(size_t)col[j + 2] * HID + tt * 8];
#pragma unroll
        for (int i = 0; i < 8; ++i) acc[i] += a0 * bf16f(v0[i]);
        a0 = a1; v0 = v1;
        a1 = a2; v1 = v2;
    }
#pragma unroll
    for (int i = 0; i < 8; ++i) acc[i] += a0 * bf16f(v0[i]);
    if (j + 1 < end) {
#pragma unroll
        for (int i = 0; i < 8; ++i) acc[i] += a1 * bf16f(v1[i]);
    }

    u16x8 o;
#pragma unroll
    for (int i = 0; i < 8; ++i) {
        float b = bias[tt * 8 + i];
        o[i] = bf16r(fmaxf(acc[i] + b, 0.f));
    }
    *(u16x8*)&hb16[(size_t)nid * HID + tt * 8] = o;
}

// ---------------- pooling + FC + log_softmax ----------------

__global__ void k_bounds(const int* __restrict__ batch, int* __restrict__ gstart,
                         int* __restrict__ gend, int N) {
    int n = blockIdx.x * 256 + threadIdx.x;
    if (n < N) {
        int g = batch[n];
        if (n == 0 || batch[n - 1] != g) gstart[g] = n;
        if (n == N - 1 || batch[n + 1] != g) gend[g] = n + 1;
    }
}

// parallel pooling: node chunks x channel chunks, per-graph register accum,
// one f32 atomicAdd per graph-boundary per thread. pooled holds SUMS.
#define PCHUNK 32
__global__ __launch_bounds__(256) void k_pool(const ushort* __restrict__ h,
                                              const int* __restrict__ batch,
                                              float* __restrict__ pooled, int N) {
    int c  = blockIdx.y * 256 + threadIdx.x;
    int n0 = blockIdx.x * PCHUNK;
    int n1 = n0 + PCHUNK; if (n1 > N) n1 = N;
    int g = batch[n0];
    float acc = 0.f;
    for (int n = n0; n < n1; ++n) {
        int gn = batch[n];
        if (gn != g) {
            atomicAdd(&pooled[g * HID + c], acc);
            acc = 0.f; g = gn;
        }
        acc += bf16f(h[(size_t)n * HID + c]);
    }
    atomicAdd(&pooled[g * HID + c], acc);
}

__global__ __launch_bounds__(256) void k_fc(const float* __restrict__ pooled,
                                            const int* __restrict__ gstart,
                                            const int* __restrict__ gend,
                                            const float* __restrict__ fcw,
                                            const float* __restrict__ fcb,
                                            float* __restrict__ out) {
    int g = blockIdx.x;
    int t = threadIdx.x;
    float invc = 1.f / fmaxf((float)(gend[g] - gstart[g]), 1.f);
    __shared__ float red[NCLS][256];
    float part[NCLS];
#pragma unroll
    for (int c = 0; c < NCLS; ++c) part[c] = 0.f;
    for (int k = t; k < HID; k += 256) {
        float v = pooled[g * HID + k] * invc;
#pragma unroll
        for (int c = 0; c < NCLS; ++c) part[c] += v * fcw[k * NCLS + c];
    }
#pragma unroll
    for (int c = 0; c < NCLS; ++c) red[c][t] = part[c];
    __syncthreads();
    for (int off = 128; off > 0; off >>= 1) {
        if (t < off) {
#pragma unroll
            for (int c = 0; c < NCLS; ++c) red[c][t] += red[c][t + off];
        }
        __syncthreads();
    }
    if (t == 0) {
        float logits[NCLS];
        float mx = -1e30f;
#pragma unroll
        for (int c = 0; c < NCLS; ++c) {
            logits[c] = red[c][0] + fcb[c];
            mx = fmaxf(mx, logits[c]);
        }
        float se = 0.f;
#pragma unroll
        for (int c = 0; c < NCLS; ++c) se += expf(logits[c] - mx);
        float lse = mx + logf(se);
#pragma unroll
        for (int c = 0; c < NCLS; ++c) out[g * NCLS + c] = logits[c] - lse;
    }
}

// ---------------- launch ----------------

extern "C" void kernel_launch(void* const* d_in, const int* in_sizes, int n_in,
                              void* d_out, int out_size, void* d_ws, size_t ws_size,
                              hipStream_t stream) {
    const float* x    = (const float*)d_in[0];
    const int*   ei   = (const int*)d_in[1];
    const int*   batch= (const int*)d_in[2];
    const float* W0   = (const float*)d_in[3];
    const float* W1   = (const float*)d_in[4];
    const float* W2   = (const float*)d_in[5];
    const float* asrc = (const float*)d_in[6];
    const float* adst = (const float*)d_in[7];
    const float* bias = (const float*)d_in[8];
    const float* fcw  = (const float*)d_in[9];
    const float* fcb  = (const float*)d_in[10];
    float* out = (float*)d_out;

    const int E = in_sizes[1] / 2;
    const int N = NNODES;
    const int NE = E + N;

    // workspace layout
    char* ws = (char*)d_ws;
    size_t off = 0;
    auto alloc = [&](size_t bytes) { void* p = ws + off; off += (bytes + 255) & ~(size_t)255; return p; };
    ushort* projb  = (ushort*)alloc((size_t)N * HID * 2);       // GEMM output (bf16)
    ushort* hb16   = (ushort*)alloc((size_t)N * HID * 2);       // layer output (bf16)
    ushort* xb16   = (ushort*)alloc((size_t)N * 512 * 2);
    ushort* w0t    = (ushort*)alloc((size_t)HID * 512 * 2);
    ushort* w1t    = (ushort*)alloc((size_t)HID * HID * 2);
    ushort* w2t    = (ushort*)alloc((size_t)HID * HID * 2);
    float*  esrc   = (float*)alloc((size_t)N * NHEADS * 4);
    float*  edst   = (float*)alloc((size_t)N * NHEADS * 4);
    float*  alphab = (float*)alloc((size_t)NE * NHEADS * 4);
    int*    counts = (int*)alloc((size_t)N * 4);
    int*    row_ptr= (int*)alloc((size_t)(N + 1) * 4);
    int*    fill   = (int*)alloc((size_t)N * 4);
    int*    col    = (int*)alloc((size_t)NE * 4);
    int*    gstart = (int*)alloc(NGRAPH * 4);
    int*    gend   = (int*)alloc(NGRAPH * 4);
    float*  pooled = (float*)alloc(NGRAPH * HID * 4);
    (void)ws_size;

    const int* srcArr = ei;
    const int* dstArr = ei + E;

    // CSR build
    hipMemsetAsync(counts, 0, (size_t)N * 4, stream);
    hipMemsetAsync(fill,   0, (size_t)N * 4, stream);
    hipMemsetAsync(gstart, 0, NGRAPH * 4, stream);
    hipMemsetAsync(gend,   0, NGRAPH * 4, stream);
    hipMemsetAsync(pooled, 0, NGRAPH * HID * 4, stream);
    int nbE = (NE + 255) / 256;
    k_hist<<<nbE, 256, 0, stream>>>(dstArr, counts, E);
    k_scan<<<1, 1024, 0, stream>>>(counts, row_ptr, N);
    k_scatter<<<nbE, 256, 0, stream>>>(srcArr, dstArr, row_ptr, fill, col, E);

    // conversions
    k_f32_to_bf16<<<(N * 512 / 4 + 255) / 256, 256, 0, stream>>>(x, xb16, N * 512 / 4);
    k_wT<<<dim3(32, 512 / 32), 256, 0, stream>>>(W0, w0t, 512);
    k_wT<<<dim3(32, HID / 32), 256, 0, stream>>>(W1, w1t, HID);
    k_wT<<<dim3(32, HID / 32), 256, 0, stream>>>(W2, w2t, HID);

    dim3 gemmGrid(HID / BN, (N + BM - 1) / BM);

    // layer 0
    k_gemm_bf16<<<gemmGrid, 256, 0, stream>>>(xb16, w0t, projb, N, 512);
    k_edotv<<<N / 4, 256, 0, stream>>>(projb, asrc + 0 * HID, adst + 0 * HID, esrc, edst);
    k_alpha<<<N / 4, 256, 0, stream>>>(esrc, edst, row_ptr, col, alphab);
    k_agg<<<N / 2, 256, 0, stream>>>(projb, alphab, row_ptr, col, bias + 0 * HID, hb16);

    // layer 1
    k_gemm_bf16<<<gemmGrid, 256, 0, stream>>>(hb16, w1t, projb, N, HID);
    k_edotv<<<N / 4, 256, 0, stream>>>(projb, asrc + 1 * HID, adst + 1 * HID, esrc, edst);
    k_alpha<<<N / 4, 256, 0, stream>>>(esrc, edst, row_ptr, col, alphab);
    k_agg<<<N / 2, 256, 0, stream>>>(projb, alphab, row_ptr, col, bias + 1 * HID, hb16);

    // layer 2
    k_gemm_bf16<<<gemmGrid, 256, 0, stream>>>(hb16, w2t, projb, N, HID);
    k_edotv<<<N / 4, 256, 0, stream>>>(projb, asrc + 2 * HID, adst + 2 * HID, esrc, edst);
    k_alpha<<<N / 4, 256, 0, stream>>>(esrc, edst, row_ptr, col, alphab);
    k_agg<<<N / 2, 256, 0, stream>>>(projb, alphab, row_ptr, col, bias + 2 * HID, hb16);

    // pool + FC + log_softmax
    k_bounds<<<(N + 255) / 256, 256, 0, stream>>>(batch, gstart, gend, N);
    dim3 poolGrid((N + PCHUNK - 1) / PCHUNK, HID / 256);
    k_pool<<<poolGrid, 256, 0, stream>>>(hb16, batch, pooled, N);
    k_fc<<<NGRAPH, 256, 0, stream>>>(pooled, gstart, gend, fcw, fcb, out);
}

// Round 7
// 348.026 us; speedup vs baseline: 3.7482x; 1.0120x over previous
//
#include <hip/hip_runtime.h>
#include <math.h>

#define NNODES 10000
#define HID    1024
#define NHEADS 4
#define NGRAPH 16
#define NCLS   10

typedef __attribute__((ext_vector_type(8))) short bf16x8;
typedef __attribute__((ext_vector_type(8))) ushort u16x8;
typedef __attribute__((ext_vector_type(4))) float f32x4;

__device__ __forceinline__ ushort bf16r(float f) {
    union { float f; unsigned u; } x; x.f = f;
    unsigned r = x.u + 0x7FFFu + ((x.u >> 16) & 1u);
    return (ushort)(r >> 16);
}
__device__ __forceinline__ float bf16f(ushort u) {
    union { unsigned u; float f; } x; x.u = ((unsigned)u) << 16;
    return x.f;
}
__device__ __forceinline__ float leaky(float e) { return e > 0.f ? e : 0.2f * e; }

// ---------------- CSR build ----------------

__global__ void k_hist(const int* __restrict__ dstArr, int* __restrict__ counts, int E) {
    int e = blockIdx.x * 256 + threadIdx.x;
    int total = E + NNODES;
    if (e < total) {
        int d = (e < E) ? dstArr[e] : (e - E);   // self-loops appended
        atomicAdd(&counts[d], 1);
    }
}

__global__ __launch_bounds__(1024) void k_scan(const int* __restrict__ counts,
                                               int* __restrict__ row_ptr, int N) {
    __shared__ int lds[1024];
    int t = threadIdx.x;
    const int C = (N + 1023) / 1024;
    int base = t * C;
    int s = 0;
    for (int i = 0; i < C; ++i)
        if (base + i < N) s += counts[base + i];
    lds[t] = s;
    __syncthreads();
    for (int off = 1; off < 1024; off <<= 1) {
        int add = (t >= off) ? lds[t - off] : 0;
        __syncthreads();
        lds[t] += add;
        __syncthreads();
    }
    int run = lds[t] - s;   // exclusive prefix
    for (int i = 0; i < C; ++i) {
        if (base + i < N) {
            row_ptr[base + i] = run;
            run += counts[base + i];
        }
    }
    if (t == 1023) row_ptr[N] = lds[1023];
}

__global__ void k_scatter(const int* __restrict__ srcArr, const int* __restrict__ dstArr,
                          const int* __restrict__ row_ptr, int* __restrict__ fill,
                          int* __restrict__ col, int E) {
    int e = blockIdx.x * 256 + threadIdx.x;
    int total = E + NNODES;
    if (e < total) {
        int s, d;
        if (e < E) { s = srcArr[e]; d = dstArr[e]; }
        else       { s = d = e - E; }
        int pos = row_ptr[d] + atomicAdd(&fill[d], 1);
        col[pos] = s;
    }
}

// ---------------- conversions ----------------

__global__ void k_f32_to_bf16(const float* __restrict__ in, ushort* __restrict__ out, int n4) {
    int i = blockIdx.x * 256 + threadIdx.x;
    if (i < n4) {
        float4 v = ((const float4*)in)[i];
        ushort4 o;
        o.x = bf16r(v.x); o.y = bf16r(v.y); o.z = bf16r(v.z); o.w = bf16r(v.w);
        ((ushort4*)out)[i] = o;
    }
}

// W [K][1024] f32 -> Wt [1024][K] bf16
__global__ __launch_bounds__(256) void k_wT(const float* __restrict__ W, ushort* __restrict__ Wt, int K) {
    __shared__ ushort tile[32][33];
    int bx = blockIdx.x;              // along N (1024/32)
    int by = blockIdx.y;              // along K
    int tx = threadIdx.x & 31, ty = threadIdx.x >> 5;   // 32 x 8
#pragma unroll
    for (int i = 0; i < 32; i += 8) {
        int k  = by * 32 + ty + i;
        int nn = bx * 32 + tx;
        tile[ty + i][tx] = bf16r(W[(size_t)k * HID + nn]);
    }
    __syncthreads();
#pragma unroll
    for (int i = 0; i < 32; i += 8) {
        int nn = bx * 32 + ty + i;
        int k  = by * 32 + tx;
        Wt[(size_t)nn * K + k] = tile[tx][ty + i];
    }
}

// ---------------- bf16 MFMA GEMM: C[M,1024] = A[M,K] * Bt[1024,K]^T, bf16 out ----------------

#define BM 128
#define BN 128
#define BK 64

__global__ __launch_bounds__(256) void k_gemm_bf16(const ushort* __restrict__ A,
                                                   const ushort* __restrict__ Bt,
                                                   ushort* __restrict__ C, int M, int K) {
    __shared__ ushort As[BM * BK];
    __shared__ ushort Bs[BN * BK];
    const int t    = threadIdx.x;
    const int lane = t & 63;
    const int w    = t >> 6;
    const int wr   = w >> 1, wc = w & 1;
    const int bm   = blockIdx.y * BM;
    const int bn   = blockIdx.x * BN;

    f32x4 acc[4][4] = {};

    const int r_  = t >> 3;          // fc = i*256+t -> row = i*32 + t>>3
    const int cp_ = t & 7;           // linear chunk within row

    for (int k0 = 0; k0 < K; k0 += BK) {
        __syncthreads();             // LDS free for overwrite
#pragma unroll
        for (int i = 0; i < 4; ++i) {
            int fc = i * 256 + t;
            int r  = i * 32 + r_;
            int c  = cp_ ^ (r & 7);  // inverse-swizzled source chunk
            int ga = bm + r; if (ga >= M) ga = M - 1;
            __builtin_amdgcn_global_load_lds(
                (const __attribute__((address_space(1))) unsigned*)&A[(size_t)ga * K + k0 + c * 8],
                (__attribute__((address_space(3))) unsigned*)&As[fc * 8], 16, 0, 0);
            __builtin_amdgcn_global_load_lds(
                (const __attribute__((address_space(1))) unsigned*)&Bt[(size_t)(bn + r) * K + k0 + c * 8],
                (__attribute__((address_space(3))) unsigned*)&Bs[fc * 8], 16, 0, 0);
        }
        __syncthreads();             // staging visible (compiler drains vmcnt)

#pragma unroll
        for (int s = 0; s < 2; ++s) {
            const int kc = s * 4 + (lane >> 4);     // k-chunk index 0..7
            bf16x8 a[4], b[4];
#pragma unroll
            for (int m = 0; m < 4; ++m) {
                int row = wr * 64 + m * 16 + (lane & 15);
                int ch  = kc ^ (row & 7);
                a[m] = *(const bf16x8*)&As[row * BK + ch * 8];
            }
#pragma unroll
            for (int n = 0; n < 4; ++n) {
                int cl = wc * 64 + n * 16 + (lane & 15);
                int ch = kc ^ (cl & 7);
                b[n] = *(const bf16x8*)&Bs[cl * BK + ch * 8];
            }
#pragma unroll
            for (int m = 0; m < 4; ++m)
#pragma unroll
                for (int n = 0; n < 4; ++n)
                    acc[m][n] = __builtin_amdgcn_mfma_f32_16x16x32_bf16(a[m], b[n], acc[m][n], 0, 0, 0);
        }
    }

    // C/D layout: col = lane&15, row = (lane>>4)*4 + j   [m89-verified]
#pragma unroll
    for (int m = 0; m < 4; ++m) {
        int row0 = bm + wr * 64 + m * 16 + (lane >> 4) * 4;
#pragma unroll
        for (int n = 0; n < 4; ++n) {
            int coln = bn + wc * 64 + n * 16 + (lane & 15);
#pragma unroll
            for (int j = 0; j < 4; ++j) {
                int row = row0 + j;
                if (row < M) C[(size_t)row * HID + coln] = bf16r(acc[m][n][j]);
            }
        }
    }
}

// ---------------- per-node attention scalars (bf16 proj) ----------------
// 1 wave per node, 4 nodes per block. lane covers 16 channels (32B).

__global__ __launch_bounds__(256) void k_edotv(const ushort* __restrict__ proj,
                                               const float* __restrict__ asrc,
                                               const float* __restrict__ adst,
                                               float* __restrict__ esrc,
                                               float* __restrict__ edst) {
    int lane = threadIdx.x & 63;
    int n = blockIdx.x * 4 + (threadIdx.x >> 6);
    int h = lane >> 4;                 // 16 lanes per head
    int c0 = lane * 16;
    u16x8 p0 = *(const u16x8*)&proj[(size_t)n * HID + c0];
    u16x8 p1 = *(const u16x8*)&proj[(size_t)n * HID + c0 + 8];
    float ds_ = 0.f, dd = 0.f;
#pragma unroll
    for (int i = 0; i < 8; ++i) {
        float v0 = bf16f(p0[i]), v1 = bf16f(p1[i]);
        ds_ += v0 * asrc[c0 + i] + v1 * asrc[c0 + 8 + i];
        dd  += v0 * adst[c0 + i] + v1 * adst[c0 + 8 + i];
    }
#pragma unroll
    for (int off = 8; off > 0; off >>= 1) {
        ds_ += __shfl_xor(ds_, off);
        dd  += __shfl_xor(dd, off);
    }
    if ((lane & 15) == 0) {
        esrc[n * NHEADS + h] = ds_;
        edst[n * NHEADS + h] = dd;
    }
}

// ---------------- per-edge normalized attention weights (transposed out) ----------------
// 1 wave per node, 4 nodes per block. Writes alphaT[h][csr_slot].

__global__ __launch_bounds__(256) void k_alpha(const float* __restrict__ esrc,
                                               const float* __restrict__ edst,
                                               const int* __restrict__ row_ptr,
                                               const int* __restrict__ col,
                                               float* __restrict__ alphaT, int nepad) {
    const int lane = threadIdx.x & 63;
    const int n = blockIdx.x * 4 + (threadIdx.x >> 6);
    const int beg = row_ptr[n], end = row_ptr[n + 1];
    const int deg = end - beg;
    const float4 ed = *(const float4*)&edst[n * 4];

    float e0[4], e1[4];
    const bool has0 = lane < deg;
    const bool has1 = lane + 64 < deg;
    float m0 = -1e30f, m1 = -1e30f, m2 = -1e30f, m3 = -1e30f;
    if (has0) {
        float4 es = *(const float4*)&esrc[col[beg + lane] * 4];
        e0[0] = leaky(es.x + ed.x); e0[1] = leaky(es.y + ed.y);
        e0[2] = leaky(es.z + ed.z); e0[3] = leaky(es.w + ed.w);
        m0 = e0[0]; m1 = e0[1]; m2 = e0[2]; m3 = e0[3];
    }
    if (has1) {
        float4 es = *(const float4*)&esrc[col[beg + 64 + lane] * 4];
        e1[0] = leaky(es.x + ed.x); e1[1] = leaky(es.y + ed.y);
        e1[2] = leaky(es.z + ed.z); e1[3] = leaky(es.w + ed.w);
        m0 = fmaxf(m0, e1[0]); m1 = fmaxf(m1, e1[1]);
        m2 = fmaxf(m2, e1[2]); m3 = fmaxf(m3, e1[3]);
    }
    for (int j = beg + 128 + lane; j < end; j += 64) {   // rare path
        float4 es = *(const float4*)&esrc[col[j] * 4];
        m0 = fmaxf(m0, leaky(es.x + ed.x)); m1 = fmaxf(m1, leaky(es.y + ed.y));
        m2 = fmaxf(m2, leaky(es.z + ed.z)); m3 = fmaxf(m3, leaky(es.w + ed.w));
    }
#pragma unroll
    for (int off = 32; off > 0; off >>= 1) {
        m0 = fmaxf(m0, __shfl_xor(m0, off)); m1 = fmaxf(m1, __shfl_xor(m1, off));
        m2 = fmaxf(m2, __shfl_xor(m2, off)); m3 = fmaxf(m3, __shfl_xor(m3, off));
    }
    float d0 = 0.f, d1 = 0.f, d2 = 0.f, d3 = 0.f;
    if (has0) {
        e0[0] = __expf(e0[0] - m0); e0[1] = __expf(e0[1] - m1);
        e0[2] = __expf(e0[2] - m2); e0[3] = __expf(e0[3] - m3);
        d0 += e0[0]; d1 += e0[1]; d2 += e0[2]; d3 += e0[3];
    }
    if (has1) {
        e1[0] = __expf(e1[0] - m0); e1[1] = __expf(e1[1] - m1);
        e1[2] = __expf(e1[2] - m2); e1[3] = __expf(e1[3] - m3);
        d0 += e1[0]; d1 += e1[1]; d2 += e1[2]; d3 += e1[3];
    }
    for (int j = beg + 128 + lane; j < end; j += 64) {   // rare path
        float4 es = *(const float4*)&esrc[col[j] * 4];
        d0 += __expf(leaky(es.x + ed.x) - m0); d1 += __expf(leaky(es.y + ed.y) - m1);
        d2 += __expf(leaky(es.z + ed.z) - m2); d3 += __expf(leaky(es.w + ed.w) - m3);
    }
#pragma unroll
    for (int off = 32; off > 0; off >>= 1) {
        d0 += __shfl_xor(d0, off); d1 += __shfl_xor(d1, off);
        d2 += __shfl_xor(d2, off); d3 += __shfl_xor(d3, off);
    }
    const float i0 = 1.f / d0, i1 = 1.f / d1, i2 = 1.f / d2, i3 = 1.f / d3;
    if (has0) {
        int j = beg + lane;
        alphaT[0 * nepad + j] = e0[0] * i0;
        alphaT[1 * nepad + j] = e0[1] * i1;
        alphaT[2 * nepad + j] = e0[2] * i2;
        alphaT[3 * nepad + j] = e0[3] * i3;
    }
    if (has1) {
        int j = beg + 64 + lane;
        alphaT[0 * nepad + j] = e1[0] * i0;
        alphaT[1 * nepad + j] = e1[1] * i1;
        alphaT[2 * nepad + j] = e1[2] * i2;
        alphaT[3 * nepad + j] = e1[3] * i3;
    }
    for (int j = beg + 128 + lane; j < end; j += 64) {   // rare path
        float4 es = *(const float4*)&esrc[col[j] * 4];
        alphaT[0 * nepad + j] = __expf(leaky(es.x + ed.x) - m0) * i0;
        alphaT[1 * nepad + j] = __expf(leaky(es.y + ed.y) - m1) * i1;
        alphaT[2 * nepad + j] = __expf(leaky(es.z + ed.z) - m2) * i2;
        alphaT[3 * nepad + j] = __expf(leaky(es.w + ed.w) - m3) * i3;
    }
}

// ---------------- aggregation: chunk-4 double-buffered gather ----------------
// 2 waves per node (128 threads x 8 ch), 2 nodes per 256-block.
// 4 row-gathers in flight per thread; col/alpha vectorized (aligned int4/float4).
// NOTE: macro internals use trailing-underscore names — must not collide with
// caller argument names (round-6 NaN bug: macro-local `b0` shadowed caller's).

__global__ __launch_bounds__(256) void k_agg(const ushort* __restrict__ proj,
                                             const float* __restrict__ alphaT,
                                             const int* __restrict__ row_ptr,
                                             const int* __restrict__ col,
                                             const float* __restrict__ bias,
                                             ushort* __restrict__ hb16, int nepad) {
    const int half = threadIdx.x >> 7;
    const int nid  = blockIdx.x * 2 + half;
    const int tt   = threadIdx.x & 127;
    const int h    = tt >> 5;
    const int beg  = row_ptr[nid], end = row_ptr[nid + 1];
    const float* aT = alphaT + (size_t)h * nepad;
    const ushort* pbase = proj + tt * 8;

    float acc[8] = {};

#define LOADCHUNK(cb, A0, A1, A2, A3, V0, V1, V2, V3)                        \
    {                                                                        \
        int4   cc_ = *(const int4*)&col[cb];                                 \
        float4 aa_ = *(const float4*)&aT[cb];                                \
        bool m0_ = ((cb) + 0 >= beg) & ((cb) + 0 < end);                     \
        bool m1_ = ((cb) + 1 >= beg) & ((cb) + 1 < end);                     \
        bool m2_ = ((cb) + 2 >= beg) & ((cb) + 2 < end);                     \
        bool m3_ = ((cb) + 3 >= beg) & ((cb) + 3 < end);                     \
        int s0_ = m0_ ? cc_.x : 0; int s1_ = m1_ ? cc_.y : 0;                \
        int s2_ = m2_ ? cc_.z : 0; int s3_ = m3_ ? cc_.w : 0;                \
        A0 = m0_ ? aa_.x : 0.f; A1 = m1_ ? aa_.y : 0.f;                      \
        A2 = m2_ ? aa_.z : 0.f; A3 = m3_ ? aa_.w : 0.f;                      \
        V0 = *(const u16x8*)&pbase[(size_t)s0_ * HID];                       \
        V1 = *(const u16x8*)&pbase[(size_t)s1_ * HID];                       \
        V2 = *(const u16x8*)&pbase[(size_t)s2_ * HID];                       \
        V3 = *(const u16x8*)&pbase[(size_t)s3_ * HID];                       \
    }

#define FMACHUNK(A0, A1, A2, A3, V0, V1, V2, V3)                             \
    {                                                                        \
        _Pragma("unroll")                                                    \
        for (int i_ = 0; i_ < 8; ++i_)                                       \
            acc[i_] += A0 * bf16f(V0[i_]) + A1 * bf16f(V1[i_])               \
                     + A2 * bf16f(V2[i_]) + A3 * bf16f(V3[i_]);              \
    }

    int c = beg & ~3;
    float a0, a1, a2, a3;
    u16x8 v0, v1, v2, v3;
    LOADCHUNK(c, a0, a1, a2, a3, v0, v1, v2, v3);
    for (c += 4; c < end; c += 4) {
        float na0, na1, na2, na3;
        u16x8 nv0, nv1, nv2, nv3;
        LOADCHUNK(c, na0, na1, na2, na3, nv0, nv1, nv2, nv3);
        FMACHUNK(a0, a1, a2, a3, v0, v1, v2, v3);
        a0 = na0; a1 = na1; a2 = na2; a3 = na3;
        v0 = nv0; v1 = nv1; v2 = nv2; v3 = nv3;
    }
    FMACHUNK(a0, a1, a2, a3, v0, v1, v2, v3);
#undef LOADCHUNK
#undef FMACHUNK

    u16x8 o;
#pragma unroll
    for (int i = 0; i < 8; ++i) {
        float b = bias[tt * 8 + i];
        o[i] = bf16r(fmaxf(acc[i] + b, 0.f));
    }
    *(u16x8*)&hb16[(size_t)nid * HID + tt * 8] = o;
}

// ---------------- pooling + FC + log_softmax ----------------

__global__ void k_bounds(const int* __restrict__ batch, int* __restrict__ gstart,
                         int* __restrict__ gend, int N) {
    int n = blockIdx.x * 256 + threadIdx.x;
    if (n < N) {
        int g = batch[n];
        if (n == 0 || batch[n - 1] != g) gstart[g] = n;
        if (n == N - 1 || batch[n + 1] != g) gend[g] = n + 1;
    }
}

// parallel pooling: node chunks x channel chunks, per-graph register accum,
// one f32 atomicAdd per graph-boundary per thread. pooled holds SUMS.
#define PCHUNK 32
__global__ __launch_bounds__(256) void k_pool(const ushort* __restrict__ h,
                                              const int* __restrict__ batch,
                                              float* __restrict__ pooled, int N) {
    int c  = blockIdx.y * 256 + threadIdx.x;
    int n0 = blockIdx.x * PCHUNK;
    int n1 = n0 + PCHUNK; if (n1 > N) n1 = N;
    int g = batch[n0];
    float acc = 0.f;
    for (int n = n0; n < n1; ++n) {
        int gn = batch[n];
        if (gn != g) {
            atomicAdd(&pooled[g * HID + c], acc);
            acc = 0.f; g = gn;
        }
        acc += bf16f(h[(size_t)n * HID + c]);
    }
    atomicAdd(&pooled[g * HID + c], acc);
}

__global__ __launch_bounds__(256) void k_fc(const float* __restrict__ pooled,
                                            const int* __restrict__ gstart,
                                            const int* __restrict__ gend,
                                            const float* __restrict__ fcw,
                                            const float* __restrict__ fcb,
                                            float* __restrict__ out) {
    int g = blockIdx.x;
    int t = threadIdx.x;
    float invc = 1.f / fmaxf((float)(gend[g] - gstart[g]), 1.f);
    __shared__ float red[NCLS][256];
    float part[NCLS];
#pragma unroll
    for (int c = 0; c < NCLS; ++c) part[c] = 0.f;
    for (int k = t; k < HID; k += 256) {
        float v = pooled[g * HID + k] * invc;
#pragma unroll
        for (int c = 0; c < NCLS; ++c) part[c] += v * fcw[k * NCLS + c];
    }
#pragma unroll
    for (int c = 0; c < NCLS; ++c) red[c][t] = part[c];
    __syncthreads();
    for (int off = 128; off > 0; off >>= 1) {
        if (t < off) {
#pragma unroll
            for (int c = 0; c < NCLS; ++c) red[c][t] += red[c][t + off];
        }
        __syncthreads();
    }
    if (t == 0) {
        float logits[NCLS];
        float mx = -1e30f;
#pragma unroll
        for (int c = 0; c < NCLS; ++c) {
            logits[c] = red[c][0] + fcb[c];
            mx = fmaxf(mx, logits[c]);
        }
        float se = 0.f;
#pragma unroll
        for (int c = 0; c < NCLS; ++c) se += expf(logits[c] - mx);
        float lse = mx + logf(se);
#pragma unroll
        for (int c = 0; c < NCLS; ++c) out[g * NCLS + c] = logits[c] - lse;
    }
}

// ---------------- launch ----------------

extern "C" void kernel_launch(void* const* d_in, const int* in_sizes, int n_in,
                              void* d_out, int out_size, void* d_ws, size_t ws_size,
                              hipStream_t stream) {
    const float* x    = (const float*)d_in[0];
    const int*   ei   = (const int*)d_in[1];
    const int*   batch= (const int*)d_in[2];
    const float* W0   = (const float*)d_in[3];
    const float* W1   = (const float*)d_in[4];
    const float* W2   = (const float*)d_in[5];
    const float* asrc = (const float*)d_in[6];
    const float* adst = (const float*)d_in[7];
    const float* bias = (const float*)d_in[8];
    const float* fcw  = (const float*)d_in[9];
    const float* fcb  = (const float*)d_in[10];
    float* out = (float*)d_out;

    const int E = in_sizes[1] / 2;
    const int N = NNODES;
    const int NE = E + N;
    const int NEPAD = ((NE + 3) & ~3) + 4;

    // workspace layout
    char* ws = (char*)d_ws;
    size_t off = 0;
    auto alloc = [&](size_t bytes) { void* p = ws + off; off += (bytes + 255) & ~(size_t)255; return p; };
    ushort* projb  = (ushort*)alloc((size_t)N * HID * 2);       // GEMM output (bf16)
    ushort* hb16   = (ushort*)alloc((size_t)N * HID * 2);       // layer output (bf16)
    ushort* xb16   = (ushort*)alloc((size_t)N * 512 * 2);
    ushort* w0t    = (ushort*)alloc((size_t)HID * 512 * 2);
    ushort* w1t    = (ushort*)alloc((size_t)HID * HID * 2);
    ushort* w2t    = (ushort*)alloc((size_t)HID * HID * 2);
    float*  esrc   = (float*)alloc((size_t)N * NHEADS * 4);
    float*  edst   = (float*)alloc((size_t)N * NHEADS * 4);
    float*  alphaT = (float*)alloc((size_t)NEPAD * NHEADS * 4);
    int*    counts = (int*)alloc((size_t)N * 4);
    int*    row_ptr= (int*)alloc((size_t)(N + 1) * 4);
    int*    fill   = (int*)alloc((size_t)N * 4);
    int*    col    = (int*)alloc((size_t)(NE + 8) * 4);
    int*    gstart = (int*)alloc(NGRAPH * 4);
    int*    gend   = (int*)alloc(NGRAPH * 4);
    float*  pooled = (float*)alloc(NGRAPH * HID * 4);
    (void)ws_size;

    const int* srcArr = ei;
    const int* dstArr = ei + E;

    // CSR build
    hipMemsetAsync(counts, 0, (size_t)N * 4, stream);
    hipMemsetAsync(fill,   0, (size_t)N * 4, stream);
    hipMemsetAsync(gstart, 0, NGRAPH * 4, stream);
    hipMemsetAsync(gend,   0, NGRAPH * 4, stream);
    hipMemsetAsync(pooled, 0, NGRAPH * HID * 4, stream);
    hipMemsetAsync(col + NE, 0, 8 * 4, stream);   // sanitize padded col slots
    int nbE = (NE + 255) / 256;
    k_hist<<<nbE, 256, 0, stream>>>(dstArr, counts, E);
    k_scan<<<1, 1024, 0, stream>>>(counts, row_ptr, N);
    k_scatter<<<nbE, 256, 0, stream>>>(srcArr, dstArr, row_ptr, fill, col, E);

    // conversions
    k_f32_to_bf16<<<(N * 512 / 4 + 255) / 256, 256, 0, stream>>>(x, xb16, N * 512 / 4);
    k_wT<<<dim3(32, 512 / 32), 256, 0, stream>>>(W0, w0t, 512);
    k_wT<<<dim3(32, HID / 32), 256, 0, stream>>>(W1, w1t, HID);
    k_wT<<<dim3(32, HID / 32), 256, 0, stream>>>(W2, w2t, HID);

    dim3 gemmGrid(HID / BN, (N + BM - 1) / BM);

    // layer 0
    k_gemm_bf16<<<gemmGrid, 256, 0, stream>>>(xb16, w0t, projb, N, 512);
    k_edotv<<<N / 4, 256, 0, stream>>>(projb, asrc + 0 * HID, adst + 0 * HID, esrc, edst);
    k_alpha<<<N / 4, 256, 0, stream>>>(esrc, edst, row_ptr, col, alphaT, NEPAD);
    k_agg<<<N / 2, 256, 0, stream>>>(projb, alphaT, row_ptr, col, bias + 0 * HID, hb16, NEPAD);

    // layer 1
    k_gemm_bf16<<<gemmGrid, 256, 0, stream>>>(hb16, w1t, projb, N, HID);
    k_edotv<<<N / 4, 256, 0, stream>>>(projb, asrc + 1 * HID, adst + 1 * HID, esrc, edst);
    k_alpha<<<N / 4, 256, 0, stream>>>(esrc, edst, row_ptr, col, alphaT, NEPAD);
    k_agg<<<N / 2, 256, 0, stream>>>(projb, alphaT, row_ptr, col, bias + 1 * HID, hb16, NEPAD);

    // layer 2
    k_gemm_bf16<<<gemmGrid, 256, 0, stream>>>(hb16, w2t, projb, N, HID);
    k_edotv<<<N / 4, 256, 0, stream>>>(projb, asrc + 2 * HID, adst + 2 * HID, esrc, edst);
    k_alpha<<<N / 4, 256, 0, stream>>>(esrc, edst, row_ptr, col, alphaT, NEPAD);
    k_agg<<<N / 2, 256, 0, stream>>>(projb, alphaT, row_ptr, col, bias + 2 * HID, hb16, NEPAD);

    // pool + FC + log_softmax
    k_bounds<<<(N + 255) / 256, 256, 0, stream>>>(batch, gstart, gend, N);
    dim3 poolGrid((N + PCHUNK - 1) / PCHUNK, HID / 256);
    k_pool<<<poolGrid, 256, 0, stream>>>(hb16, batch, pooled, N);
    k_fc<<<NGRAPH, 256, 0, stream>>>(pooled, gstart, gend, fcw, fcb, out);
}